// Round 5
// baseline (179.897 us; speedup 1.0000x reference)
//
#include <hip/hip_runtime.h>
#include <math.h>

#define BB 8
#define NVV 2048
#define NPP 4096
#define DD 64
#define NQ (BB * NVV)     // 16384 vertex rows
#define QT (NQ / 16)      // 1024 query tiles
#define NC1 2             // key chunks KNN1 (128 tiles each)
#define NC2 2             // key chunks KNN2 (64 tiles each)

typedef __attribute__((ext_vector_type(8))) short short8;
typedef __attribute__((ext_vector_type(8))) unsigned short ushort8;
typedef __attribute__((ext_vector_type(4))) float f32x4;

// ws layout (float offsets), audited line-by-line (R10 lesson):
// vm      @0        (16384)
// inv_vf_s@16384    (16384)   = 16384/norm
// inv_pf_s@32768    (32768)
// flow    @65536    (65536)
// pc1     @131072   (16*16384 uints = 262144)
// pc2     @393216   (16*16384 uints = 262144)
// vfh     @655360   (QT*1024 ushorts = 524288 floats)
// vfl     @1179648  (+524288)
// pfh     @1703936  (2048 tiles*1024 ushorts = 1048576 floats)
// pfl     @2752512  (+1048576)
// end     @3801088  floats = 14.5 MB

__device__ __forceinline__ unsigned short bf16rn(float x) {
  unsigned u = __float_as_uint(x);
  return (unsigned short)((u + 0x7FFFu + ((u >> 16) & 1u)) >> 16);
}
__device__ __forceinline__ float bf2f(unsigned short h) {
  return __uint_as_float(((unsigned)h) << 16);
}

// Branchless sorted-ascending top-8 insert: 7x v_med3_u32 + 1x max.
__device__ __forceinline__ void net8(unsigned* a, unsigned v) {
#pragma unroll
  for (int k = 0; k < 7; k++) {
    unsigned r;
    asm("v_med3_u32 %0, %1, %2, %3" : "=v"(r) : "v"(v), "v"(a[k]), "v"(a[k + 1]));
    a[k] = r;
  }
  a[7] = a[7] > v ? a[7] : v;
}

__device__ __forceinline__ void ins8(float* tv, int* ti, float v, int id) {
  bool c1 = v > tv[1], c2 = v > tv[2], c3 = v > tv[3];
  bool c4 = v > tv[4], c5 = v > tv[5], c6 = v > tv[6], c7 = v > tv[7];
  tv[0] = c1 ? tv[1] : v;                ti[0] = c1 ? ti[1] : id;
  tv[1] = c2 ? tv[2] : (c1 ? v : tv[1]); ti[1] = c2 ? ti[2] : (c1 ? id : ti[1]);
  tv[2] = c3 ? tv[3] : (c2 ? v : tv[2]); ti[2] = c3 ? ti[3] : (c2 ? id : ti[2]);
  tv[3] = c4 ? tv[4] : (c3 ? v : tv[3]); ti[3] = c4 ? ti[4] : (c3 ? id : ti[3]);
  tv[4] = c5 ? tv[5] : (c4 ? v : tv[4]); ti[4] = c5 ? ti[5] : (c4 ? id : ti[4]);
  tv[5] = c6 ? tv[6] : (c5 ? v : tv[5]); ti[5] = c6 ? ti[6] : (c5 ? id : ti[5]);
  tv[6] = c7 ? tv[7] : (c6 ? v : tv[6]); ti[6] = c7 ? ti[7] : (c6 ? id : ti[6]);
  tv[7] = c7 ? v : tv[7];                ti[7] = c7 ? id : ti[7];
}

// ===== kernel 1: vm (blocks 0..7) + wave-per-tile norm+normalize+staging =====
__global__ __launch_bounds__(256) void k_prep(const float* __restrict__ logits,
                                              const float* __restrict__ vf,
                                              const float* __restrict__ pf,
                                              float* __restrict__ vm,
                                              float* __restrict__ inv_vf_s,
                                              float* __restrict__ inv_pf_s,
                                              unsigned short* __restrict__ vfh,
                                              unsigned short* __restrict__ vfl,
                                              unsigned short* __restrict__ pfh,
                                              unsigned short* __restrict__ pfl,
                                              float* __restrict__ out) {
  int bid = blockIdx.x, t = threadIdx.x;
  if (bid < BB) {
    int b = bid;
    __shared__ float smn[4], smx[4];
    float vals[8];
    float mn = 1e30f, mx = -1e30f;
#pragma unroll
    for (int i = 0; i < 8; i++) {
      float x = logits[b * NVV + t + i * 256];
      float s = 1.0f / (1.0f + expf(-x));
      vals[i] = s;
      mn = fminf(mn, s);
      mx = fmaxf(mx, s);
    }
    for (int o = 32; o; o >>= 1) {
      mn = fminf(mn, __shfl_xor(mn, o, 64));
      mx = fmaxf(mx, __shfl_xor(mx, o, 64));
    }
    int w = t >> 6;
    if ((t & 63) == 0) { smn[w] = mn; smx[w] = mx; }
    __syncthreads();
    mn = fminf(fminf(smn[0], smn[1]), fminf(smn[2], smn[3]));
    mx = fmaxf(fmaxf(smx[0], smx[1]), fmaxf(smx[2], smx[3]));
    float range = mx - mn;
#pragma unroll
    for (int i = 0; i < 8; i++) {
      float v = (vals[i] - mn) / range;
      int g = b * NVV + t + i * 256;
      vm[g] = v;
      out[g * 4 + 3] = v;
    }
  } else {
    // 4 tiles per block (one per wave); 3072 tiles total; vf/pf split at
    // tile 1024 (4-aligned -> no block straddles)
    int tile_g = (bid - BB) * 4 + (t >> 6);
    int lane = t & 63, c = lane & 15, quad = (lane >> 4) & 3;
    const float* src;
    unsigned short *dh, *dl;
    float* ginv;
    int tile;
    if (tile_g < QT) { tile = tile_g; src = vf; dh = vfh; dl = vfl; ginv = inv_vf_s; }
    else { tile = tile_g - QT; src = pf; dh = pfh; dl = pfl; ginv = inv_pf_s; }
    int row = tile * 16 + c;
    const float* rp = src + (size_t)row * DD + quad * 8;
    float4 a0 = *(const float4*)(rp);
    float4 b0 = *(const float4*)(rp + 4);
    float4 a1 = *(const float4*)(rp + 32);
    float4 b1 = *(const float4*)(rp + 36);
    float xs[16] = {a0.x, a0.y, a0.z, a0.w, b0.x, b0.y, b0.z, b0.w,
                    a1.x, a1.y, a1.z, a1.w, b1.x, b1.y, b1.z, b1.w};
    float ss = 0.f;
#pragma unroll
    for (int j = 0; j < 16; j++) ss = fmaf(xs[j], xs[j], ss);
    ss += __shfl_xor(ss, 16, 64);
    ss += __shfl_xor(ss, 32, 64);   // all quads now hold the row total
    float inv = 1.0f / fmaxf(sqrtf(ss), 1e-12f);
    if (quad == 0) ginv[row] = 16384.0f * inv;  // pow2 scale: exact ratio later
    ushort8 h, l;
    size_t s0 = (size_t)tile * 128 + lane;      // kk=0 slot
#pragma unroll
    for (int j = 0; j < 8; j++) {
      float xn = xs[j] * inv;
      unsigned short hj = bf16rn(xn);
      h[j] = hj;
      l[j] = bf16rn(xn - bf2f(hj));
    }
    *(ushort8*)(dh + s0 * 8) = h;
    *(ushort8*)(dl + s0 * 8) = l;
#pragma unroll
    for (int j = 0; j < 8; j++) {
      float xn = xs[8 + j] * inv;
      unsigned short hj = bf16rn(xn);
      h[j] = hj;
      l[j] = bf16rn(xn - bf2f(hj));
    }
    *(ushort8*)(dh + (s0 + 64) * 8) = h;      // kk=1 slot
    *(ushort8*)(dl + (s0 + 64) * 8) = l;
  }
}

// ===== kernel 2: MFMA KNN candidate generation (fused KNN1 + KNN2) =====
// R18: R17 confirmed keys are L2-resident (FETCH 50.7->6.2 MB) but wall
// unchanged -> VALU-issue-dominated (67%) with ~28% latency/dep stalls
// that 4 waves/SIMD can't cover. This round: split each (qtile,chunk)
// across TWO waves (64/32 tiles each), exact top-8 union-merge via 1 KB
// LDS at the end -> 8192 waves = 8/SIMD, pc contents bit-identical, pc
// layout and merge kernels untouched. XCD batch-pinning preserved
// (p and p+1024 share an XCD since 1024%8==0).
__global__ __launch_bounds__(256)
void k_knn(const unsigned short* __restrict__ vfh, const unsigned short* __restrict__ vfl,
           const unsigned short* __restrict__ pfh, const unsigned short* __restrict__ pfl,
           const float* __restrict__ vm,
           unsigned* __restrict__ pc1, unsigned* __restrict__ pc2) {
  __shared__ unsigned mg[2][16][8];

  int p = blockIdx.x;                 // 0..2047
  int tid = threadIdx.x;
  int pairid = tid >> 7;              // which (qtile,chunk) unit in block
  int wv = (tid >> 6) & 1;            // wave within the pair
  int lane = tid & 63, col = lane & 15, quad = lane >> 4;

  bool knn1 = p < 1024;
  int q8 = knn1 ? p : (p - 1024);
  int xcd = q8 & 7, idx = q8 >> 3;
  int lb = xcd * 128 + idx;           // logical block in section; batch = lb>>7 = xcd
  int unit = lb * 2 + pairid;         // (qtile,chunk) unit id in section
  int ck = unit & 1;
  int qt_g = unit >> 1;               // 0..1023
  int batch = qt_g >> 7;              // == xcd by construction

  const unsigned short *KH, *KL;
  const float* mask;
  unsigned* PC;
  int bt0, tilebase, half, row0;
  if (knn1) {            // KNN1: keys = pf, 2 chunks x 128 tiles, 64/wave
    KH = pfh; KL = pfl;
    mask = nullptr;
    half = 64;
    bt0 = batch * 256 + ck * 128 + wv * 64;
    tilebase = ck * 128 + wv * 64;
    PC = pc1;
    row0 = ck * 8;
  } else {               // KNN2: keys = vf, visible only, 2 chunks x 64 tiles, 32/wave
    KH = vfh; KL = vfl;
    mask = vm + batch * NVV;
    half = 32;
    bt0 = batch * 128 + ck * 64 + wv * 32;
    tilebase = ck * 64 + wv * 32;
    PC = pc2;
    row0 = ck * 8;
  }

  size_t ab = (size_t)qt_g * 1024 + lane * 8;
  short8 qh0 = *(const short8*)(vfh + ab);
  short8 qh1 = *(const short8*)(vfh + ab + 512);
  short8 ql0 = *(const short8*)(vfl + ab);
  short8 ql1 = *(const short8*)(vfl + ab + 512);
  // Pin loop-invariant query frags in AGPRs: free homes (MFMA reads AGPR
  // A/B operands directly), keeps arch-VGPR count low for 8 waves/SIMD.
  asm volatile("" : "+a"(qh0), "+a"(qh1), "+a"(ql0), "+a"(ql1));

  unsigned tv[8];
#pragma unroll
  for (int k = 0; k < 8; k++) tv[k] = 0u;

#pragma unroll 2
  for (int kt = 0; kt < half; kt++) {
    size_t bo = (size_t)(bt0 + kt) * 1024 + lane * 8;
    short8 kh0 = *(const short8*)(KH + bo);
    short8 kh1 = *(const short8*)(KH + bo + 512);
    short8 kl0 = *(const short8*)(KL + bo);
    short8 kl1 = *(const short8*)(KL + bo + 512);
    int base16 = (tilebase + kt) * 16;
    f32x4 c = {0.f, 0.f, 0.f, 0.f};
    c = __builtin_amdgcn_mfma_f32_16x16x32_bf16(kh0, qh0, c, 0, 0, 0);
    c = __builtin_amdgcn_mfma_f32_16x16x32_bf16(kh1, qh1, c, 0, 0, 0);
    c = __builtin_amdgcn_mfma_f32_16x16x32_bf16(kh0, ql0, c, 0, 0, 0);
    c = __builtin_amdgcn_mfma_f32_16x16x32_bf16(kh1, ql1, c, 0, 0, 0);
    c = __builtin_amdgcn_mfma_f32_16x16x32_bf16(kl0, qh0, c, 0, 0, 0);
    c = __builtin_amdgcn_mfma_f32_16x16x32_bf16(kl1, qh1, c, 0, 0, 0);
    float4 mv;
    if (mask) mv = *(const float4*)(mask + base16 + quad * 4);
#pragma unroll
    for (int r = 0; r < 4; r++) {
      unsigned u = (unsigned)fmaxf(fmaf(c[r], 520000.0f, 520000.0f), 0.0f);
      unsigned pk = (u << 12) | (unsigned)(base16 + quad * 4 + r);
      if (mask) {
        float mr = (r == 0) ? mv.x : (r == 1) ? mv.y : (r == 2) ? mv.z : mv.w;
        pk = (mr >= 0.5f) ? pk : 0u;
      }
      net8(tv, pk);
    }
  }

  // butterfly across the 4 quads (lane bits 4,5) -- all quads end identical
#pragma unroll
  for (int m = 16; m <= 32; m <<= 1) {
    unsigned ov[8];
#pragma unroll
    for (int k = 0; k < 8; k++) ov[k] = (unsigned)__shfl_xor((int)tv[k], m, 64);
#pragma unroll
    for (int k = 7; k >= 0; k--) net8(tv, ov[k]);
  }

  // exact cross-wave union merge: top8(A ∪ B) = top8(top8(A) ∪ top8(B))
  if (wv == 1 && lane < 16) {
#pragma unroll
    for (int k = 0; k < 8; k++) mg[pairid][lane][k] = tv[k];
  }
  __syncthreads();
  if (wv == 0 && lane < 16) {
#pragma unroll
    for (int k = 0; k < 8; k++) net8(tv, mg[pairid][lane][k]);
    int q = qt_g * 16 + lane;
#pragma unroll
    for (int k = 0; k < 8; k++)
      PC[(size_t)(row0 + k) * NQ + q] = tv[k];
  }
}

__device__ __forceinline__ float dot64(const float4* __restrict__ a,
                                       const float4* __restrict__ b) {
  float a0 = 0.f, a1 = 0.f, a2 = 0.f, a3 = 0.f;
#pragma unroll
  for (int c = 0; c < 16; c++) {
    float4 x = a[c], y = b[c];
    a0 = fmaf(x.x, y.x, a0);
    a1 = fmaf(x.y, y.y, a1);
    a2 = fmaf(x.z, y.z, a2);
    a3 = fmaf(x.w, y.w, a3);
  }
  return (a0 + a1) + (a2 + a3);
}

// ===== kernel 3: exact re-rank of 16 KNN1 candidates + flow_init (16 lanes/q) =====
__global__ __launch_bounds__(256) void k_merge_flow(const unsigned* __restrict__ pc,
                                                    const float* __restrict__ vf,
                                                    const float* __restrict__ pf,
                                                    const float* __restrict__ pts,
                                                    const float* __restrict__ vtx,
                                                    const float* __restrict__ inv_pf_s,
                                                    float* __restrict__ flow_ws,
                                                    float* __restrict__ out) {
  int T = blockIdx.x * 256 + threadIdx.x;
  int q = T >> 4, c = T & 15, batch = q >> 11;
  const float4* qp = (const float4*)(vf + (size_t)q * DD);
  float tv[8];
  int ti[8];
#pragma unroll
  for (int k = 0; k < 8; k++) { tv[k] = -3.0e38f; ti[k] = 0; }
  {  // 16 candidate rows / 16 lanes (KNN1 pk always valid)
    unsigned pk = pc[(size_t)c * NQ + q];
    int id = (int)(pk & 0xFFFu);
    int prow = batch * NPP + id;
    float s = dot64(qp, (const float4*)(pf + (size_t)prow * DD)) *
              inv_pf_s[prow] * 6.103515625e-5f;  // * 2^-14 (exact)
    ins8(tv, ti, s, id);
  }
#pragma unroll
  for (int m = 1; m <= 8; m <<= 1) {
    float ov[8];
    int oi[8];
#pragma unroll
    for (int k = 0; k < 8; k++) {
      ov[k] = __shfl_xor(tv[k], m, 64);
      oi[k] = __shfl_xor(ti[k], m, 64);
    }
#pragma unroll
    for (int k = 7; k >= 0; k--)
      if (ov[k] > tv[0]) ins8(tv, ti, ov[k], oi[k]);
  }
  int id = ti[0];
  float sv = tv[0];
#pragma unroll
  for (int k = 1; k < 8; k++) {
    id = (c == k) ? ti[k] : id;
    sv = (c == k) ? tv[k] : sv;
  }

  float ax = 0.f, ay = 0.f, az = 0.f, den = 0.f;
  if (c < 8) {
    int prow = batch * NPP + id;
    float w = sv * 16384.0f / inv_pf_s[prow];  // = raw dot (exact pow2 ratio)
    ax = (pts[prow * 3 + 0] - vtx[q * 3 + 0]) * w;
    ay = (pts[prow * 3 + 1] - vtx[q * 3 + 1]) * w;
    az = (pts[prow * 3 + 2] - vtx[q * 3 + 2]) * w;
    den = w;
  }
#pragma unroll
  for (int m = 1; m <= 8; m <<= 1) {
    ax += __shfl_xor(ax, m, 64);
    ay += __shfl_xor(ay, m, 64);
    az += __shfl_xor(az, m, 64);
    den += __shfl_xor(den, m, 64);
  }
  if (c == 0) {
    float fx = ax / den, fy = ay / den, fz = az / den;
    flow_ws[q * 4 + 0] = fx;
    flow_ws[q * 4 + 1] = fy;
    flow_ws[q * 4 + 2] = fz;
    out[q * 4 + 0] = fx;
    out[q * 4 + 1] = fy;
    out[q * 4 + 2] = fz;
  }
}

// ===== kernel 4: exact re-rank of 16 KNN2 candidates + interpolate invisible =====
__global__ __launch_bounds__(256) void k_merge_final(const unsigned* __restrict__ pc,
                                                     const float* __restrict__ vf,
                                                     const float* __restrict__ vm,
                                                     const float* __restrict__ inv_vf_s,
                                                     const float* __restrict__ flow_ws,
                                                     float* __restrict__ out) {
  int T = blockIdx.x * 256 + threadIdx.x;
  int q = T >> 4, c = T & 15, batch = q >> 11;
  if (vm[q] >= 0.5f) return;
  const float4* qp = (const float4*)(vf + (size_t)q * DD);
  float tv[8];
  int ti[8];
#pragma unroll
  for (int k = 0; k < 8; k++) { tv[k] = -3.0e38f; ti[k] = 0; }
  {  // pk <= 0xFFF = masked sentinel, skip
    unsigned pk = pc[(size_t)c * NQ + q];
    if (pk > 0xFFFu) {
      int id = (int)(pk & 0xFFFu);
      int krow = batch * NVV + id;
      float s = dot64(qp, (const float4*)(vf + (size_t)krow * DD)) *
                inv_vf_s[krow] * 6.103515625e-5f;
      ins8(tv, ti, s, id);
    }
  }
#pragma unroll
  for (int m = 1; m <= 8; m <<= 1) {
    float ov[8];
    int oi[8];
#pragma unroll
    for (int k = 0; k < 8; k++) {
      ov[k] = __shfl_xor(tv[k], m, 64);
      oi[k] = __shfl_xor(ti[k], m, 64);
    }
#pragma unroll
    for (int k = 7; k >= 0; k--)
      if (ov[k] > tv[0]) ins8(tv, ti, ov[k], oi[k]);
  }
  int id = ti[0];
  float sv = tv[0];
#pragma unroll
  for (int k = 1; k < 8; k++) {
    id = (c == k) ? ti[k] : id;
    sv = (c == k) ? tv[k] : sv;
  }

  float ax = 0.f, ay = 0.f, az = 0.f, den = 0.f;
  if (c < 8) {
    int krow = batch * NVV + id;
    float w = sv * 16384.0f / inv_vf_s[krow];
    ax = flow_ws[krow * 4 + 0] * w;
    ay = flow_ws[krow * 4 + 1] * w;
    az = flow_ws[krow * 4 + 2] * w;
    den = w;
  }
#pragma unroll
  for (int m = 1; m <= 8; m <<= 1) {
    ax += __shfl_xor(ax, m, 64);
    ay += __shfl_xor(ay, m, 64);
    az += __shfl_xor(az, m, 64);
    den += __shfl_xor(den, m, 64);
  }
  if (c == 0) {
    out[q * 4 + 0] = ax / den;
    out[q * 4 + 1] = ay / den;
    out[q * 4 + 2] = az / den;
  }
}

extern "C" void kernel_launch(void* const* d_in, const int* in_sizes, int n_in,
                              void* d_out, int out_size, void* d_ws, size_t ws_size,
                              hipStream_t stream) {
  const float* vtx = (const float*)d_in[0];
  const float* pts = (const float*)d_in[1];
  const float* vf = (const float*)d_in[2];
  const float* pf = (const float*)d_in[3];
  const float* lg = (const float*)d_in[4];
  float* out = (float*)d_out;
  float* ws = (float*)d_ws;

  float* vm = ws;
  float* inv_vf_s = ws + 16384;
  float* inv_pf_s = ws + 32768;
  float* flow = ws + 65536;
  unsigned* pc1 = (unsigned*)(ws + 131072);
  unsigned* pc2 = (unsigned*)(ws + 393216);
  unsigned short* vfh = (unsigned short*)(ws + 655360);
  unsigned short* vfl = (unsigned short*)(ws + 1179648);   // +524288 floats
  unsigned short* pfh = (unsigned short*)(ws + 1703936);   // +524288
  unsigned short* pfl = (unsigned short*)(ws + 2752512);   // +1048576

  k_prep<<<BB + 768, 256, 0, stream>>>(lg, vf, pf, vm, inv_vf_s, inv_pf_s,
                                       vfh, vfl, pfh, pfl, out);
  k_knn<<<2048, 256, 0, stream>>>(vfh, vfl, pfh, pfl, vm, pc1, pc2);
  k_merge_flow<<<NQ * 16 / 256, 256, 0, stream>>>(pc1, vf, pf, pts, vtx,
                                                  inv_pf_s, flow, out);
  k_merge_final<<<NQ * 16 / 256, 256, 0, stream>>>(pc2, vf, vm, inv_vf_s, flow, out);
}

// Round 6
// 174.936 us; speedup vs baseline: 1.0284x; 1.0284x over previous
//
#include <hip/hip_runtime.h>
#include <math.h>

#define BB 8
#define NVV 2048
#define NPP 4096
#define DD 64
#define NQ (BB * NVV)     // 16384 vertex rows
#define QT (NQ / 16)      // 1024 query tiles
#define NC1 2             // key chunks KNN1 (128 tiles each)
#define NC2 2             // key chunks KNN2 (64 tiles each)

typedef __attribute__((ext_vector_type(8))) short short8;
typedef __attribute__((ext_vector_type(8))) unsigned short ushort8;
typedef __attribute__((ext_vector_type(4))) float f32x4;

// ws layout (float offsets), audited line-by-line (R10 lesson):
// vm      @0        (16384)
// inv_vf_s@16384    (16384)   = 16384/norm
// inv_pf_s@32768    (32768)
// flow    @65536    (65536)
// pc1     @131072   (16*16384 uints = 262144)
// pc2     @393216   (16*16384 uints = 262144)
// vfh     @655360   (QT*1024 ushorts = 524288 floats)
// vfl     @1179648  (+524288)
// pfh     @1703936  (2048 tiles*1024 ushorts = 1048576 floats)
// pfl     @2752512  (+1048576)
// end     @3801088  floats = 14.5 MB

__device__ __forceinline__ unsigned short bf16rn(float x) {
  unsigned u = __float_as_uint(x);
  return (unsigned short)((u + 0x7FFFu + ((u >> 16) & 1u)) >> 16);
}
__device__ __forceinline__ float bf2f(unsigned short h) {
  return __uint_as_float(((unsigned)h) << 16);
}

// Branchless sorted-ascending top-8 insert: 7x v_med3_u32 + 1x max.
__device__ __forceinline__ void net8(unsigned* a, unsigned v) {
#pragma unroll
  for (int k = 0; k < 7; k++) {
    unsigned r;
    asm("v_med3_u32 %0, %1, %2, %3" : "=v"(r) : "v"(v), "v"(a[k]), "v"(a[k + 1]));
    a[k] = r;
  }
  a[7] = a[7] > v ? a[7] : v;
}

__device__ __forceinline__ void ins8(float* tv, int* ti, float v, int id) {
  bool c1 = v > tv[1], c2 = v > tv[2], c3 = v > tv[3];
  bool c4 = v > tv[4], c5 = v > tv[5], c6 = v > tv[6], c7 = v > tv[7];
  tv[0] = c1 ? tv[1] : v;                ti[0] = c1 ? ti[1] : id;
  tv[1] = c2 ? tv[2] : (c1 ? v : tv[1]); ti[1] = c2 ? ti[2] : (c1 ? id : ti[1]);
  tv[2] = c3 ? tv[3] : (c2 ? v : tv[2]); ti[2] = c3 ? ti[3] : (c2 ? id : ti[2]);
  tv[3] = c4 ? tv[4] : (c3 ? v : tv[3]); ti[3] = c4 ? ti[4] : (c3 ? id : ti[3]);
  tv[4] = c5 ? tv[5] : (c4 ? v : tv[4]); ti[4] = c5 ? ti[5] : (c4 ? id : ti[4]);
  tv[5] = c6 ? tv[6] : (c5 ? v : tv[5]); ti[5] = c6 ? ti[6] : (c5 ? id : ti[5]);
  tv[6] = c7 ? tv[7] : (c6 ? v : tv[6]); ti[6] = c7 ? ti[7] : (c6 ? id : ti[6]);
  tv[7] = c7 ? v : tv[7];                ti[7] = c7 ? id : ti[7];
}

// ===== kernel 1: vm (blocks 0..7) + wave-per-tile norm+normalize+staging =====
__global__ __launch_bounds__(256) void k_prep(const float* __restrict__ logits,
                                              const float* __restrict__ vf,
                                              const float* __restrict__ pf,
                                              float* __restrict__ vm,
                                              float* __restrict__ inv_vf_s,
                                              float* __restrict__ inv_pf_s,
                                              unsigned short* __restrict__ vfh,
                                              unsigned short* __restrict__ vfl,
                                              unsigned short* __restrict__ pfh,
                                              unsigned short* __restrict__ pfl,
                                              float* __restrict__ out) {
  int bid = blockIdx.x, t = threadIdx.x;
  if (bid < BB) {
    int b = bid;
    __shared__ float smn[4], smx[4];
    float vals[8];
    float mn = 1e30f, mx = -1e30f;
#pragma unroll
    for (int i = 0; i < 8; i++) {
      float x = logits[b * NVV + t + i * 256];
      float s = 1.0f / (1.0f + expf(-x));
      vals[i] = s;
      mn = fminf(mn, s);
      mx = fmaxf(mx, s);
    }
    for (int o = 32; o; o >>= 1) {
      mn = fminf(mn, __shfl_xor(mn, o, 64));
      mx = fmaxf(mx, __shfl_xor(mx, o, 64));
    }
    int w = t >> 6;
    if ((t & 63) == 0) { smn[w] = mn; smx[w] = mx; }
    __syncthreads();
    mn = fminf(fminf(smn[0], smn[1]), fminf(smn[2], smn[3]));
    mx = fmaxf(fmaxf(smx[0], smx[1]), fmaxf(smx[2], smx[3]));
    float range = mx - mn;
#pragma unroll
    for (int i = 0; i < 8; i++) {
      float v = (vals[i] - mn) / range;
      int g = b * NVV + t + i * 256;
      vm[g] = v;
      out[g * 4 + 3] = v;
    }
  } else {
    // 4 tiles per block (one per wave); 3072 tiles total; vf/pf split at
    // tile 1024 (4-aligned -> no block straddles)
    int tile_g = (bid - BB) * 4 + (t >> 6);
    int lane = t & 63, c = lane & 15, quad = (lane >> 4) & 3;
    const float* src;
    unsigned short *dh, *dl;
    float* ginv;
    int tile;
    if (tile_g < QT) { tile = tile_g; src = vf; dh = vfh; dl = vfl; ginv = inv_vf_s; }
    else { tile = tile_g - QT; src = pf; dh = pfh; dl = pfl; ginv = inv_pf_s; }
    int row = tile * 16 + c;
    const float* rp = src + (size_t)row * DD + quad * 8;
    float4 a0 = *(const float4*)(rp);
    float4 b0 = *(const float4*)(rp + 4);
    float4 a1 = *(const float4*)(rp + 32);
    float4 b1 = *(const float4*)(rp + 36);
    float xs[16] = {a0.x, a0.y, a0.z, a0.w, b0.x, b0.y, b0.z, b0.w,
                    a1.x, a1.y, a1.z, a1.w, b1.x, b1.y, b1.z, b1.w};
    float ss = 0.f;
#pragma unroll
    for (int j = 0; j < 16; j++) ss = fmaf(xs[j], xs[j], ss);
    ss += __shfl_xor(ss, 16, 64);
    ss += __shfl_xor(ss, 32, 64);   // all quads now hold the row total
    float inv = 1.0f / fmaxf(sqrtf(ss), 1e-12f);
    if (quad == 0) ginv[row] = 16384.0f * inv;  // pow2 scale: exact ratio later
    ushort8 h, l;
    size_t s0 = (size_t)tile * 128 + lane;      // kk=0 slot
#pragma unroll
    for (int j = 0; j < 8; j++) {
      float xn = xs[j] * inv;
      unsigned short hj = bf16rn(xn);
      h[j] = hj;
      l[j] = bf16rn(xn - bf2f(hj));
    }
    *(ushort8*)(dh + s0 * 8) = h;
    *(ushort8*)(dl + s0 * 8) = l;
#pragma unroll
    for (int j = 0; j < 8; j++) {
      float xn = xs[8 + j] * inv;
      unsigned short hj = bf16rn(xn);
      h[j] = hj;
      l[j] = bf16rn(xn - bf2f(hj));
    }
    *(ushort8*)(dh + (s0 + 64) * 8) = h;      // kk=1 slot
    *(ushort8*)(dl + (s0 + 64) * 8) = l;
  }
}

// ===== kernel 2: MFMA KNN candidate generation (fused KNN1 + KNN2) =====
// R19: cross-round data (R0/15/16/17/18) shows VALU-cyc per chain-visit is
// pinned at ~320 regardless of waves/SIMD or key bytes -> VALU-throughput-
// bound; the 61-67% VALUBusy ceiling was workload-imbalance TAILS (KNN2
// waves/blocks finish at half-time; 4 blocks/CU -> no backfill). Fix:
// every wave gets an IDENTICAL 96-visit schedule = one KNN1 half-chunk
// (64 tiles) + one KNN2 half-chunk (32 tiles). 4096 waves x 96 = all
// 393216 visits; 1024 equal blocks = 4/CU resident start-to-finish, zero
// tail. Half-pairs union-merge exactly in LDS (R18-proven); pc1/pc2
// bit-identical; merge kernels untouched; XCD batch-pinning kept.
__global__ __launch_bounds__(256)
void k_knn(const unsigned short* __restrict__ vfh, const unsigned short* __restrict__ vfl,
           const unsigned short* __restrict__ pfh, const unsigned short* __restrict__ pfl,
           const float* __restrict__ vm,
           unsigned* __restrict__ pc1, unsigned* __restrict__ pc2) {
  __shared__ unsigned mg[2][2][16][8];   // [section][ck][col][k]

  int p = blockIdx.x;                 // 0..1023
  int xcd = p & 7, j = p >> 3;        // batch pin: batch == xcd
  int qt_g = xcd * 128 + j;           // this block's query tile
  int batch = xcd;
  int w = (int)threadIdx.x >> 6;      // wave 0..3
  int ck = w >> 1, hf = w & 1;        // chunk, half within chunk
  int lane = threadIdx.x & 63, col = lane & 15, quad = lane >> 4;

  // query frags once per wave (serve both phases)
  size_t ab = (size_t)qt_g * 1024 + lane * 8;
  short8 qh0 = *(const short8*)(vfh + ab);
  short8 qh1 = *(const short8*)(vfh + ab + 512);
  short8 ql0 = *(const short8*)(vfl + ab);
  short8 ql1 = *(const short8*)(vfl + ab + 512);
  // Pin loop-invariant query frags in AGPRs: MFMA reads AGPR A/B natively.
  asm volatile("" : "+a"(qh0), "+a"(qh1), "+a"(ql0), "+a"(ql1));

  unsigned tv[8];

  // ---------------- phase A: KNN1 (keys = pf), 64 tiles ----------------
#pragma unroll
  for (int k = 0; k < 8; k++) tv[k] = 0u;
  {
    int bt0 = batch * 256 + ck * 128 + hf * 64;
    int tb = ck * 128 + hf * 64;
#pragma unroll 2
    for (int kt = 0; kt < 64; kt++) {
      size_t bo = (size_t)(bt0 + kt) * 1024 + lane * 8;
      short8 kh0 = *(const short8*)(pfh + bo);
      short8 kh1 = *(const short8*)(pfh + bo + 512);
      short8 kl0 = *(const short8*)(pfl + bo);
      short8 kl1 = *(const short8*)(pfl + bo + 512);
      int base16 = (tb + kt) * 16;
      f32x4 c = {0.f, 0.f, 0.f, 0.f};
      c = __builtin_amdgcn_mfma_f32_16x16x32_bf16(kh0, qh0, c, 0, 0, 0);
      c = __builtin_amdgcn_mfma_f32_16x16x32_bf16(kh1, qh1, c, 0, 0, 0);
      c = __builtin_amdgcn_mfma_f32_16x16x32_bf16(kh0, ql0, c, 0, 0, 0);
      c = __builtin_amdgcn_mfma_f32_16x16x32_bf16(kh1, ql1, c, 0, 0, 0);
      c = __builtin_amdgcn_mfma_f32_16x16x32_bf16(kl0, qh0, c, 0, 0, 0);
      c = __builtin_amdgcn_mfma_f32_16x16x32_bf16(kl1, qh1, c, 0, 0, 0);
#pragma unroll
      for (int r = 0; r < 4; r++) {
        unsigned u = (unsigned)fmaxf(fmaf(c[r], 520000.0f, 520000.0f), 0.0f);
        unsigned pk = (u << 12) | (unsigned)(base16 + quad * 4 + r);
        net8(tv, pk);
      }
    }
  }
  // butterfly across quads (lane bits 4,5) -- all quads end identical
#pragma unroll
  for (int m = 16; m <= 32; m <<= 1) {
    unsigned ov[8];
#pragma unroll
    for (int k = 0; k < 8; k++) ov[k] = (unsigned)__shfl_xor((int)tv[k], m, 64);
#pragma unroll
    for (int k = 7; k >= 0; k--) net8(tv, ov[k]);
  }
  if (hf == 1 && quad == 0) {
#pragma unroll
    for (int k = 0; k < 8; k++) mg[0][ck][col][k] = tv[k];
  }
  __syncthreads();
  if (hf == 0 && quad == 0) {
#pragma unroll
    for (int k = 0; k < 8; k++) net8(tv, mg[0][ck][col][k]);
    int q = qt_g * 16 + col;
#pragma unroll
    for (int k = 0; k < 8; k++)
      pc1[(size_t)(ck * 8 + k) * NQ + q] = tv[k];
  }

  // ---------------- phase B: KNN2 (keys = vf, visible only), 32 tiles ----
#pragma unroll
  for (int k = 0; k < 8; k++) tv[k] = 0u;
  {
    const float* mask = vm + batch * NVV;
    int bt0 = batch * 128 + ck * 64 + hf * 32;
    int tb = ck * 64 + hf * 32;
#pragma unroll 2
    for (int kt = 0; kt < 32; kt++) {
      size_t bo = (size_t)(bt0 + kt) * 1024 + lane * 8;
      short8 kh0 = *(const short8*)(vfh + bo);
      short8 kh1 = *(const short8*)(vfh + bo + 512);
      short8 kl0 = *(const short8*)(vfl + bo);
      short8 kl1 = *(const short8*)(vfl + bo + 512);
      int base16 = (tb + kt) * 16;
      f32x4 c = {0.f, 0.f, 0.f, 0.f};
      c = __builtin_amdgcn_mfma_f32_16x16x32_bf16(kh0, qh0, c, 0, 0, 0);
      c = __builtin_amdgcn_mfma_f32_16x16x32_bf16(kh1, qh1, c, 0, 0, 0);
      c = __builtin_amdgcn_mfma_f32_16x16x32_bf16(kh0, ql0, c, 0, 0, 0);
      c = __builtin_amdgcn_mfma_f32_16x16x32_bf16(kh1, ql1, c, 0, 0, 0);
      c = __builtin_amdgcn_mfma_f32_16x16x32_bf16(kl0, qh0, c, 0, 0, 0);
      c = __builtin_amdgcn_mfma_f32_16x16x32_bf16(kl1, qh1, c, 0, 0, 0);
      float4 mv = *(const float4*)(mask + base16 + quad * 4);
#pragma unroll
      for (int r = 0; r < 4; r++) {
        unsigned u = (unsigned)fmaxf(fmaf(c[r], 520000.0f, 520000.0f), 0.0f);
        unsigned pk = (u << 12) | (unsigned)(base16 + quad * 4 + r);
        float mr = (r == 0) ? mv.x : (r == 1) ? mv.y : (r == 2) ? mv.z : mv.w;
        pk = (mr >= 0.5f) ? pk : 0u;
        net8(tv, pk);
      }
    }
  }
#pragma unroll
  for (int m = 16; m <= 32; m <<= 1) {
    unsigned ov[8];
#pragma unroll
    for (int k = 0; k < 8; k++) ov[k] = (unsigned)__shfl_xor((int)tv[k], m, 64);
#pragma unroll
    for (int k = 7; k >= 0; k--) net8(tv, ov[k]);
  }
  if (hf == 1 && quad == 0) {
#pragma unroll
    for (int k = 0; k < 8; k++) mg[1][ck][col][k] = tv[k];
  }
  __syncthreads();
  if (hf == 0 && quad == 0) {
#pragma unroll
    for (int k = 0; k < 8; k++) net8(tv, mg[1][ck][col][k]);
    int q = qt_g * 16 + col;
#pragma unroll
    for (int k = 0; k < 8; k++)
      pc2[(size_t)(ck * 8 + k) * NQ + q] = tv[k];
  }
}

__device__ __forceinline__ float dot64(const float4* __restrict__ a,
                                       const float4* __restrict__ b) {
  float a0 = 0.f, a1 = 0.f, a2 = 0.f, a3 = 0.f;
#pragma unroll
  for (int c = 0; c < 16; c++) {
    float4 x = a[c], y = b[c];
    a0 = fmaf(x.x, y.x, a0);
    a1 = fmaf(x.y, y.y, a1);
    a2 = fmaf(x.z, y.z, a2);
    a3 = fmaf(x.w, y.w, a3);
  }
  return (a0 + a1) + (a2 + a3);
}

// ===== kernel 3: exact re-rank of 16 KNN1 candidates + flow_init (16 lanes/q) =====
__global__ __launch_bounds__(256) void k_merge_flow(const unsigned* __restrict__ pc,
                                                    const float* __restrict__ vf,
                                                    const float* __restrict__ pf,
                                                    const float* __restrict__ pts,
                                                    const float* __restrict__ vtx,
                                                    const float* __restrict__ inv_pf_s,
                                                    float* __restrict__ flow_ws,
                                                    float* __restrict__ out) {
  int T = blockIdx.x * 256 + threadIdx.x;
  int q = T >> 4, c = T & 15, batch = q >> 11;
  const float4* qp = (const float4*)(vf + (size_t)q * DD);
  float tv[8];
  int ti[8];
#pragma unroll
  for (int k = 0; k < 8; k++) { tv[k] = -3.0e38f; ti[k] = 0; }
  {  // 16 candidate rows / 16 lanes (KNN1 pk always valid)
    unsigned pk = pc[(size_t)c * NQ + q];
    int id = (int)(pk & 0xFFFu);
    int prow = batch * NPP + id;
    float s = dot64(qp, (const float4*)(pf + (size_t)prow * DD)) *
              inv_pf_s[prow] * 6.103515625e-5f;  // * 2^-14 (exact)
    ins8(tv, ti, s, id);
  }
#pragma unroll
  for (int m = 1; m <= 8; m <<= 1) {
    float ov[8];
    int oi[8];
#pragma unroll
    for (int k = 0; k < 8; k++) {
      ov[k] = __shfl_xor(tv[k], m, 64);
      oi[k] = __shfl_xor(ti[k], m, 64);
    }
#pragma unroll
    for (int k = 7; k >= 0; k--)
      if (ov[k] > tv[0]) ins8(tv, ti, ov[k], oi[k]);
  }
  int id = ti[0];
  float sv = tv[0];
#pragma unroll
  for (int k = 1; k < 8; k++) {
    id = (c == k) ? ti[k] : id;
    sv = (c == k) ? tv[k] : sv;
  }

  float ax = 0.f, ay = 0.f, az = 0.f, den = 0.f;
  if (c < 8) {
    int prow = batch * NPP + id;
    float w = sv * 16384.0f / inv_pf_s[prow];  // = raw dot (exact pow2 ratio)
    ax = (pts[prow * 3 + 0] - vtx[q * 3 + 0]) * w;
    ay = (pts[prow * 3 + 1] - vtx[q * 3 + 1]) * w;
    az = (pts[prow * 3 + 2] - vtx[q * 3 + 2]) * w;
    den = w;
  }
#pragma unroll
  for (int m = 1; m <= 8; m <<= 1) {
    ax += __shfl_xor(ax, m, 64);
    ay += __shfl_xor(ay, m, 64);
    az += __shfl_xor(az, m, 64);
    den += __shfl_xor(den, m, 64);
  }
  if (c == 0) {
    float fx = ax / den, fy = ay / den, fz = az / den;
    flow_ws[q * 4 + 0] = fx;
    flow_ws[q * 4 + 1] = fy;
    flow_ws[q * 4 + 2] = fz;
    out[q * 4 + 0] = fx;
    out[q * 4 + 1] = fy;
    out[q * 4 + 2] = fz;
  }
}

// ===== kernel 4: exact re-rank of 16 KNN2 candidates + interpolate invisible =====
__global__ __launch_bounds__(256) void k_merge_final(const unsigned* __restrict__ pc,
                                                     const float* __restrict__ vf,
                                                     const float* __restrict__ vm,
                                                     const float* __restrict__ inv_vf_s,
                                                     const float* __restrict__ flow_ws,
                                                     float* __restrict__ out) {
  int T = blockIdx.x * 256 + threadIdx.x;
  int q = T >> 4, c = T & 15, batch = q >> 11;
  if (vm[q] >= 0.5f) return;
  const float4* qp = (const float4*)(vf + (size_t)q * DD);
  float tv[8];
  int ti[8];
#pragma unroll
  for (int k = 0; k < 8; k++) { tv[k] = -3.0e38f; ti[k] = 0; }
  {  // pk <= 0xFFF = masked sentinel, skip
    unsigned pk = pc[(size_t)c * NQ + q];
    if (pk > 0xFFFu) {
      int id = (int)(pk & 0xFFFu);
      int krow = batch * NVV + id;
      float s = dot64(qp, (const float4*)(vf + (size_t)krow * DD)) *
                inv_vf_s[krow] * 6.103515625e-5f;
      ins8(tv, ti, s, id);
    }
  }
#pragma unroll
  for (int m = 1; m <= 8; m <<= 1) {
    float ov[8];
    int oi[8];
#pragma unroll
    for (int k = 0; k < 8; k++) {
      ov[k] = __shfl_xor(tv[k], m, 64);
      oi[k] = __shfl_xor(ti[k], m, 64);
    }
#pragma unroll
    for (int k = 7; k >= 0; k--)
      if (ov[k] > tv[0]) ins8(tv, ti, ov[k], oi[k]);
  }
  int id = ti[0];
  float sv = tv[0];
#pragma unroll
  for (int k = 1; k < 8; k++) {
    id = (c == k) ? ti[k] : id;
    sv = (c == k) ? tv[k] : sv;
  }

  float ax = 0.f, ay = 0.f, az = 0.f, den = 0.f;
  if (c < 8) {
    int krow = batch * NVV + id;
    float w = sv * 16384.0f / inv_vf_s[krow];
    ax = flow_ws[krow * 4 + 0] * w;
    ay = flow_ws[krow * 4 + 1] * w;
    az = flow_ws[krow * 4 + 2] * w;
    den = w;
  }
#pragma unroll
  for (int m = 1; m <= 8; m <<= 1) {
    ax += __shfl_xor(ax, m, 64);
    ay += __shfl_xor(ay, m, 64);
    az += __shfl_xor(az, m, 64);
    den += __shfl_xor(den, m, 64);
  }
  if (c == 0) {
    out[q * 4 + 0] = ax / den;
    out[q * 4 + 1] = ay / den;
    out[q * 4 + 2] = az / den;
  }
}

extern "C" void kernel_launch(void* const* d_in, const int* in_sizes, int n_in,
                              void* d_out, int out_size, void* d_ws, size_t ws_size,
                              hipStream_t stream) {
  const float* vtx = (const float*)d_in[0];
  const float* pts = (const float*)d_in[1];
  const float* vf = (const float*)d_in[2];
  const float* pf = (const float*)d_in[3];
  const float* lg = (const float*)d_in[4];
  float* out = (float*)d_out;
  float* ws = (float*)d_ws;

  float* vm = ws;
  float* inv_vf_s = ws + 16384;
  float* inv_pf_s = ws + 32768;
  float* flow = ws + 65536;
  unsigned* pc1 = (unsigned*)(ws + 131072);
  unsigned* pc2 = (unsigned*)(ws + 393216);
  unsigned short* vfh = (unsigned short*)(ws + 655360);
  unsigned short* vfl = (unsigned short*)(ws + 1179648);   // +524288 floats
  unsigned short* pfh = (unsigned short*)(ws + 1703936);   // +524288
  unsigned short* pfl = (unsigned short*)(ws + 2752512);   // +1048576

  k_prep<<<BB + 768, 256, 0, stream>>>(lg, vf, pf, vm, inv_vf_s, inv_pf_s,
                                       vfh, vfl, pfh, pfl, out);
  k_knn<<<1024, 256, 0, stream>>>(vfh, vfl, pfh, pfl, vm, pc1, pc2);
  k_merge_flow<<<NQ * 16 / 256, 256, 0, stream>>>(pc1, vf, pf, pts, vtx,
                                                  inv_pf_s, flow, out);
  k_merge_final<<<NQ * 16 / 256, 256, 0, stream>>>(pc2, vf, vm, inv_vf_s, flow, out);
}

// Round 7
// 174.688 us; speedup vs baseline: 1.0298x; 1.0014x over previous
//
#include <hip/hip_runtime.h>
#include <math.h>

#define BB 8
#define NVV 2048
#define NPP 4096
#define DD 64
#define NQ (BB * NVV)     // 16384 vertex rows
#define QT (NQ / 16)      // 1024 query tiles

typedef __attribute__((ext_vector_type(8))) short short8;
typedef __attribute__((ext_vector_type(8))) unsigned short ushort8;
typedef __attribute__((ext_vector_type(4))) float f32x4;

// ws layout (float offsets), audited line-by-line (R10 lesson):
// vm      @0        (16384)
// inv_vf_s@16384    (16384)   = 16384/norm
// inv_pf_s@32768    (32768)
// flow    @65536    (65536)
// pc1     @131072   (16*16384 uints = 262144)
// pc2     @393216   (16*16384 uints = 262144)
// vfh     @655360   (QT*1024 ushorts = 524288 floats)
// vfl     @1179648  (+524288)
// pfh     @1703936  (2048 tiles*1024 ushorts = 1048576 floats)
// pfl     @2752512  (+1048576)
// end     @3801088  floats = 14.5 MB

__device__ __forceinline__ unsigned short bf16rn(float x) {
  unsigned u = __float_as_uint(x);
  return (unsigned short)((u + 0x7FFFu + ((u >> 16) & 1u)) >> 16);
}
__device__ __forceinline__ float bf2f(unsigned short h) {
  return __uint_as_float(((unsigned)h) << 16);
}

// Branchless sorted-ascending top-8 insert: 7x v_med3_u32 + 1x max.
__device__ __forceinline__ void net8(unsigned* a, unsigned v) {
#pragma unroll
  for (int k = 0; k < 7; k++) {
    unsigned r;
    asm("v_med3_u32 %0, %1, %2, %3" : "=v"(r) : "v"(v), "v"(a[k]), "v"(a[k + 1]));
    a[k] = r;
  }
  a[7] = a[7] > v ? a[7] : v;
}

__device__ __forceinline__ void ins8(float* tv, int* ti, float v, int id) {
  bool c1 = v > tv[1], c2 = v > tv[2], c3 = v > tv[3];
  bool c4 = v > tv[4], c5 = v > tv[5], c6 = v > tv[6], c7 = v > tv[7];
  tv[0] = c1 ? tv[1] : v;                ti[0] = c1 ? ti[1] : id;
  tv[1] = c2 ? tv[2] : (c1 ? v : tv[1]); ti[1] = c2 ? ti[2] : (c1 ? id : ti[1]);
  tv[2] = c3 ? tv[3] : (c2 ? v : tv[2]); ti[2] = c3 ? ti[3] : (c2 ? id : ti[2]);
  tv[3] = c4 ? tv[4] : (c3 ? v : tv[3]); ti[3] = c4 ? ti[4] : (c3 ? id : ti[3]);
  tv[4] = c5 ? tv[5] : (c4 ? v : tv[4]); ti[4] = c5 ? ti[5] : (c4 ? id : ti[4]);
  tv[5] = c6 ? tv[6] : (c5 ? v : tv[5]); ti[5] = c6 ? ti[6] : (c5 ? id : ti[5]);
  tv[6] = c7 ? tv[7] : (c6 ? v : tv[6]); ti[6] = c7 ? ti[7] : (c6 ? id : ti[6]);
  tv[7] = c7 ? v : tv[7];                ti[7] = c7 ? id : ti[7];
}

// ===== kernel 1: vm (blocks 0..7) + wave-per-tile norm+normalize+staging =====
__global__ __launch_bounds__(256) void k_prep(const float* __restrict__ logits,
                                              const float* __restrict__ vf,
                                              const float* __restrict__ pf,
                                              float* __restrict__ vm,
                                              float* __restrict__ inv_vf_s,
                                              float* __restrict__ inv_pf_s,
                                              unsigned short* __restrict__ vfh,
                                              unsigned short* __restrict__ vfl,
                                              unsigned short* __restrict__ pfh,
                                              unsigned short* __restrict__ pfl,
                                              float* __restrict__ out) {
  int bid = blockIdx.x, t = threadIdx.x;
  if (bid < BB) {
    int b = bid;
    __shared__ float smn[4], smx[4];
    float vals[8];
    float mn = 1e30f, mx = -1e30f;
#pragma unroll
    for (int i = 0; i < 8; i++) {
      float x = logits[b * NVV + t + i * 256];
      float s = 1.0f / (1.0f + expf(-x));
      vals[i] = s;
      mn = fminf(mn, s);
      mx = fmaxf(mx, s);
    }
    for (int o = 32; o; o >>= 1) {
      mn = fminf(mn, __shfl_xor(mn, o, 64));
      mx = fmaxf(mx, __shfl_xor(mx, o, 64));
    }
    int w = t >> 6;
    if ((t & 63) == 0) { smn[w] = mn; smx[w] = mx; }
    __syncthreads();
    mn = fminf(fminf(smn[0], smn[1]), fminf(smn[2], smn[3]));
    mx = fmaxf(fmaxf(smx[0], smx[1]), fmaxf(smx[2], smx[3]));
    float range = mx - mn;
#pragma unroll
    for (int i = 0; i < 8; i++) {
      float v = (vals[i] - mn) / range;
      int g = b * NVV + t + i * 256;
      vm[g] = v;
      out[g * 4 + 3] = v;
    }
  } else {
    // 4 tiles per block (one per wave); 3072 tiles total; vf/pf split at
    // tile 1024 (4-aligned -> no block straddles)
    int tile_g = (bid - BB) * 4 + (t >> 6);
    int lane = t & 63, c = lane & 15, quad = (lane >> 4) & 3;
    const float* src;
    unsigned short *dh, *dl;
    float* ginv;
    int tile;
    if (tile_g < QT) { tile = tile_g; src = vf; dh = vfh; dl = vfl; ginv = inv_vf_s; }
    else { tile = tile_g - QT; src = pf; dh = pfh; dl = pfl; ginv = inv_pf_s; }
    int row = tile * 16 + c;
    const float* rp = src + (size_t)row * DD + quad * 8;
    float4 a0 = *(const float4*)(rp);
    float4 b0 = *(const float4*)(rp + 4);
    float4 a1 = *(const float4*)(rp + 32);
    float4 b1 = *(const float4*)(rp + 36);
    float xs[16] = {a0.x, a0.y, a0.z, a0.w, b0.x, b0.y, b0.z, b0.w,
                    a1.x, a1.y, a1.z, a1.w, b1.x, b1.y, b1.z, b1.w};
    float ss = 0.f;
#pragma unroll
    for (int j = 0; j < 16; j++) ss = fmaf(xs[j], xs[j], ss);
    ss += __shfl_xor(ss, 16, 64);
    ss += __shfl_xor(ss, 32, 64);   // all quads now hold the row total
    float inv = 1.0f / fmaxf(sqrtf(ss), 1e-12f);
    if (quad == 0) ginv[row] = 16384.0f * inv;  // pow2 scale: exact ratio later
    ushort8 h, l;
    size_t s0 = (size_t)tile * 128 + lane;      // kk=0 slot
#pragma unroll
    for (int j = 0; j < 8; j++) {
      float xn = xs[j] * inv;
      unsigned short hj = bf16rn(xn);
      h[j] = hj;
      l[j] = bf16rn(xn - bf2f(hj));
    }
    *(ushort8*)(dh + s0 * 8) = h;
    *(ushort8*)(dl + s0 * 8) = l;
#pragma unroll
    for (int j = 0; j < 8; j++) {
      float xn = xs[8 + j] * inv;
      unsigned short hj = bf16rn(xn);
      h[j] = hj;
      l[j] = bf16rn(xn - bf2f(hj));
    }
    *(ushort8*)(dh + (s0 + 64) * 8) = h;      // kk=1 slot
    *(ushort8*)(dl + (s0 + 64) * 8) = l;
  }
}

// ===== kernel 2: MFMA KNN candidate generation (fused KNN1 + KNN2) =====
// R20: wall is ~505 cyc/visit scaling ONLY with compute (R15-R19 nulls:
// waves, bytes, latency-tier, balance). Diagnosis: within-wave critical
// path (6 chained MFMA + 32-deep dependent med3 chain) + convoy stalls
// at the un-pipelined key loads. Fix: (1) explicit 2-deep register
// software-pipeline (load tile k+1 into named B-set before computing
// tile k -> load latency hides under compute); (2) split top-8 into two
// independent chains tvA (r=0,1) / tvB (r=2,3), exact union-merge at
// phase end -> per-visit dep chain halves. Top-8 of a fixed multiset is
// insertion-order-independent -> pc1/pc2 bit-identical; merges untouched.
// R19's balanced structure, XCD pinning, LDS union-merge all preserved.

#define LOADK(d0, d1, d2, d3, KH, KL, tile) do {            \
    size_t bo_ = (size_t)(tile) * 1024 + lane * 8;          \
    d0 = *(const short8*)((KH) + bo_);                      \
    d1 = *(const short8*)((KH) + bo_ + 512);                \
    d2 = *(const short8*)((KL) + bo_);                      \
    d3 = *(const short8*)((KL) + bo_ + 512);                \
  } while (0)

#define MFMA6(c_, h0_, h1_, l0_, l1_) do {                                  \
    c_ = __builtin_amdgcn_mfma_f32_16x16x32_bf16(h0_, qh0, c_, 0, 0, 0);    \
    c_ = __builtin_amdgcn_mfma_f32_16x16x32_bf16(h1_, qh1, c_, 0, 0, 0);    \
    c_ = __builtin_amdgcn_mfma_f32_16x16x32_bf16(h0_, ql0, c_, 0, 0, 0);    \
    c_ = __builtin_amdgcn_mfma_f32_16x16x32_bf16(h1_, ql1, c_, 0, 0, 0);    \
    c_ = __builtin_amdgcn_mfma_f32_16x16x32_bf16(l0_, qh0, c_, 0, 0, 0);    \
    c_ = __builtin_amdgcn_mfma_f32_16x16x32_bf16(l1_, qh1, c_, 0, 0, 0);    \
  } while (0)

#define COMP1(h0_, h1_, l0_, l1_, b16_) do {                                \
    f32x4 c_ = {0.f, 0.f, 0.f, 0.f};                                        \
    MFMA6(c_, h0_, h1_, l0_, l1_);                                          \
    unsigned u0_ = (unsigned)fmaxf(fmaf(c_[0], 520000.0f, 520000.0f), 0.0f);\
    net8(tvA, (u0_ << 12) | (unsigned)((b16_) + 0));                        \
    unsigned u1_ = (unsigned)fmaxf(fmaf(c_[1], 520000.0f, 520000.0f), 0.0f);\
    net8(tvA, (u1_ << 12) | (unsigned)((b16_) + 1));                        \
    unsigned u2_ = (unsigned)fmaxf(fmaf(c_[2], 520000.0f, 520000.0f), 0.0f);\
    net8(tvB, (u2_ << 12) | (unsigned)((b16_) + 2));                        \
    unsigned u3_ = (unsigned)fmaxf(fmaf(c_[3], 520000.0f, 520000.0f), 0.0f);\
    net8(tvB, (u3_ << 12) | (unsigned)((b16_) + 3));                        \
  } while (0)

#define COMP2(h0_, h1_, l0_, l1_, b16_, mp_) do {                           \
    float4 mv_ = *(const float4*)(mp_);                                     \
    f32x4 c_ = {0.f, 0.f, 0.f, 0.f};                                        \
    MFMA6(c_, h0_, h1_, l0_, l1_);                                          \
    unsigned u0_ = (unsigned)fmaxf(fmaf(c_[0], 520000.0f, 520000.0f), 0.0f);\
    unsigned p0_ = (u0_ << 12) | (unsigned)((b16_) + 0);                    \
    net8(tvA, (mv_.x >= 0.5f) ? p0_ : 0u);                                  \
    unsigned u1_ = (unsigned)fmaxf(fmaf(c_[1], 520000.0f, 520000.0f), 0.0f);\
    unsigned p1_ = (u1_ << 12) | (unsigned)((b16_) + 1);                    \
    net8(tvA, (mv_.y >= 0.5f) ? p1_ : 0u);                                  \
    unsigned u2_ = (unsigned)fmaxf(fmaf(c_[2], 520000.0f, 520000.0f), 0.0f);\
    unsigned p2_ = (u2_ << 12) | (unsigned)((b16_) + 2);                    \
    net8(tvB, (mv_.z >= 0.5f) ? p2_ : 0u);                                  \
    unsigned u3_ = (unsigned)fmaxf(fmaf(c_[3], 520000.0f, 520000.0f), 0.0f);\
    unsigned p3_ = (u3_ << 12) | (unsigned)((b16_) + 3);                    \
    net8(tvB, (mv_.w >= 0.5f) ? p3_ : 0u);                                  \
  } while (0)

__global__ __launch_bounds__(256)
void k_knn(const unsigned short* __restrict__ vfh, const unsigned short* __restrict__ vfl,
           const unsigned short* __restrict__ pfh, const unsigned short* __restrict__ pfl,
           const float* __restrict__ vm,
           unsigned* __restrict__ pc1, unsigned* __restrict__ pc2) {
  __shared__ unsigned mg[2][2][16][8];   // [section][ck][col][k]

  int p = blockIdx.x;                 // 0..1023
  int xcd = p & 7, j = p >> 3;        // batch pin: batch == xcd
  int qt_g = xcd * 128 + j;           // this block's query tile
  int batch = xcd;
  int w = (int)threadIdx.x >> 6;      // wave 0..3
  int ck = w >> 1, hf = w & 1;        // chunk, half within chunk
  int lane = threadIdx.x & 63, col = lane & 15, quad = lane >> 4;

  // query frags once per wave (serve both phases)
  size_t ab = (size_t)qt_g * 1024 + lane * 8;
  short8 qh0 = *(const short8*)(vfh + ab);
  short8 qh1 = *(const short8*)(vfh + ab + 512);
  short8 ql0 = *(const short8*)(vfl + ab);
  short8 ql1 = *(const short8*)(vfl + ab + 512);
  // Pin loop-invariant query frags in AGPRs: MFMA reads AGPR A/B natively.
  asm volatile("" : "+a"(qh0), "+a"(qh1), "+a"(ql0), "+a"(ql1));

  unsigned tvA[8], tvB[8];

  // ---------------- phase A: KNN1 (keys = pf), 64 tiles ----------------
#pragma unroll
  for (int k = 0; k < 8; k++) { tvA[k] = 0u; tvB[k] = 0u; }
  {
    int bt0 = batch * 256 + ck * 128 + hf * 64;
    int tb16 = (ck * 128 + hf * 64) * 16 + quad * 4;
    short8 ah0, ah1, al0, al1, bh0, bh1, bl0, bl1;
    LOADK(ah0, ah1, al0, al1, pfh, pfl, bt0);
#pragma unroll 1
    for (int kt = 0; kt < 62; kt += 2) {
      LOADK(bh0, bh1, bl0, bl1, pfh, pfl, bt0 + kt + 1);
      COMP1(ah0, ah1, al0, al1, tb16 + kt * 16);
      LOADK(ah0, ah1, al0, al1, pfh, pfl, bt0 + kt + 2);
      COMP1(bh0, bh1, bl0, bl1, tb16 + (kt + 1) * 16);
    }
    LOADK(bh0, bh1, bl0, bl1, pfh, pfl, bt0 + 63);
    COMP1(ah0, ah1, al0, al1, tb16 + 62 * 16);
    COMP1(bh0, bh1, bl0, bl1, tb16 + 63 * 16);
  }
  // exact union of the two chains
#pragma unroll
  for (int k = 0; k < 8; k++) net8(tvA, tvB[k]);
  // butterfly across quads (lane bits 4,5) -- all quads end identical
#pragma unroll
  for (int m = 16; m <= 32; m <<= 1) {
    unsigned ov[8];
#pragma unroll
    for (int k = 0; k < 8; k++) ov[k] = (unsigned)__shfl_xor((int)tvA[k], m, 64);
#pragma unroll
    for (int k = 7; k >= 0; k--) net8(tvA, ov[k]);
  }
  if (hf == 1 && quad == 0) {
#pragma unroll
    for (int k = 0; k < 8; k++) mg[0][ck][col][k] = tvA[k];
  }
  __syncthreads();
  if (hf == 0 && quad == 0) {
#pragma unroll
    for (int k = 0; k < 8; k++) net8(tvA, mg[0][ck][col][k]);
    int q = qt_g * 16 + col;
#pragma unroll
    for (int k = 0; k < 8; k++)
      pc1[(size_t)(ck * 8 + k) * NQ + q] = tvA[k];
  }

  // ---------------- phase B: KNN2 (keys = vf, visible only), 32 tiles ----
#pragma unroll
  for (int k = 0; k < 8; k++) { tvA[k] = 0u; tvB[k] = 0u; }
  {
    const float* mask = vm + batch * NVV;
    int bt0 = batch * 128 + ck * 64 + hf * 32;
    int tbase = ck * 64 + hf * 32;
    int tb16 = tbase * 16 + quad * 4;
    const float* mp0 = mask + tbase * 16 + quad * 4;
    short8 ah0, ah1, al0, al1, bh0, bh1, bl0, bl1;
    LOADK(ah0, ah1, al0, al1, vfh, vfl, bt0);
#pragma unroll 1
    for (int kt = 0; kt < 30; kt += 2) {
      LOADK(bh0, bh1, bl0, bl1, vfh, vfl, bt0 + kt + 1);
      COMP2(ah0, ah1, al0, al1, tb16 + kt * 16, mp0 + kt * 16);
      LOADK(ah0, ah1, al0, al1, vfh, vfl, bt0 + kt + 2);
      COMP2(bh0, bh1, bl0, bl1, tb16 + (kt + 1) * 16, mp0 + (kt + 1) * 16);
    }
    LOADK(bh0, bh1, bl0, bl1, vfh, vfl, bt0 + 31);
    COMP2(ah0, ah1, al0, al1, tb16 + 30 * 16, mp0 + 30 * 16);
    COMP2(bh0, bh1, bl0, bl1, tb16 + 31 * 16, mp0 + 31 * 16);
  }
#pragma unroll
  for (int k = 0; k < 8; k++) net8(tvA, tvB[k]);
#pragma unroll
  for (int m = 16; m <= 32; m <<= 1) {
    unsigned ov[8];
#pragma unroll
    for (int k = 0; k < 8; k++) ov[k] = (unsigned)__shfl_xor((int)tvA[k], m, 64);
#pragma unroll
    for (int k = 7; k >= 0; k--) net8(tvA, ov[k]);
  }
  if (hf == 1 && quad == 0) {
#pragma unroll
    for (int k = 0; k < 8; k++) mg[1][ck][col][k] = tvA[k];
  }
  __syncthreads();
  if (hf == 0 && quad == 0) {
#pragma unroll
    for (int k = 0; k < 8; k++) net8(tvA, mg[1][ck][col][k]);
    int q = qt_g * 16 + col;
#pragma unroll
    for (int k = 0; k < 8; k++)
      pc2[(size_t)(ck * 8 + k) * NQ + q] = tvA[k];
  }
}

__device__ __forceinline__ float dot64(const float4* __restrict__ a,
                                       const float4* __restrict__ b) {
  float a0 = 0.f, a1 = 0.f, a2 = 0.f, a3 = 0.f;
#pragma unroll
  for (int c = 0; c < 16; c++) {
    float4 x = a[c], y = b[c];
    a0 = fmaf(x.x, y.x, a0);
    a1 = fmaf(x.y, y.y, a1);
    a2 = fmaf(x.z, y.z, a2);
    a3 = fmaf(x.w, y.w, a3);
  }
  return (a0 + a1) + (a2 + a3);
}

// ===== kernel 3: exact re-rank of 16 KNN1 candidates + flow_init (16 lanes/q) =====
__global__ __launch_bounds__(256) void k_merge_flow(const unsigned* __restrict__ pc,
                                                    const float* __restrict__ vf,
                                                    const float* __restrict__ pf,
                                                    const float* __restrict__ pts,
                                                    const float* __restrict__ vtx,
                                                    const float* __restrict__ inv_pf_s,
                                                    float* __restrict__ flow_ws,
                                                    float* __restrict__ out) {
  int T = blockIdx.x * 256 + threadIdx.x;
  int q = T >> 4, c = T & 15, batch = q >> 11;
  const float4* qp = (const float4*)(vf + (size_t)q * DD);
  float tv[8];
  int ti[8];
#pragma unroll
  for (int k = 0; k < 8; k++) { tv[k] = -3.0e38f; ti[k] = 0; }
  {  // 16 candidate rows / 16 lanes (KNN1 pk always valid)
    unsigned pk = pc[(size_t)c * NQ + q];
    int id = (int)(pk & 0xFFFu);
    int prow = batch * NPP + id;
    float s = dot64(qp, (const float4*)(pf + (size_t)prow * DD)) *
              inv_pf_s[prow] * 6.103515625e-5f;  // * 2^-14 (exact)
    ins8(tv, ti, s, id);
  }
#pragma unroll
  for (int m = 1; m <= 8; m <<= 1) {
    float ov[8];
    int oi[8];
#pragma unroll
    for (int k = 0; k < 8; k++) {
      ov[k] = __shfl_xor(tv[k], m, 64);
      oi[k] = __shfl_xor(ti[k], m, 64);
    }
#pragma unroll
    for (int k = 7; k >= 0; k--)
      if (ov[k] > tv[0]) ins8(tv, ti, ov[k], oi[k]);
  }
  int id = ti[0];
  float sv = tv[0];
#pragma unroll
  for (int k = 1; k < 8; k++) {
    id = (c == k) ? ti[k] : id;
    sv = (c == k) ? tv[k] : sv;
  }

  float ax = 0.f, ay = 0.f, az = 0.f, den = 0.f;
  if (c < 8) {
    int prow = batch * NPP + id;
    float w = sv * 16384.0f / inv_pf_s[prow];  // = raw dot (exact pow2 ratio)
    ax = (pts[prow * 3 + 0] - vtx[q * 3 + 0]) * w;
    ay = (pts[prow * 3 + 1] - vtx[q * 3 + 1]) * w;
    az = (pts[prow * 3 + 2] - vtx[q * 3 + 2]) * w;
    den = w;
  }
#pragma unroll
  for (int m = 1; m <= 8; m <<= 1) {
    ax += __shfl_xor(ax, m, 64);
    ay += __shfl_xor(ay, m, 64);
    az += __shfl_xor(az, m, 64);
    den += __shfl_xor(den, m, 64);
  }
  if (c == 0) {
    float fx = ax / den, fy = ay / den, fz = az / den;
    flow_ws[q * 4 + 0] = fx;
    flow_ws[q * 4 + 1] = fy;
    flow_ws[q * 4 + 2] = fz;
    out[q * 4 + 0] = fx;
    out[q * 4 + 1] = fy;
    out[q * 4 + 2] = fz;
  }
}

// ===== kernel 4: exact re-rank of 16 KNN2 candidates + interpolate invisible =====
__global__ __launch_bounds__(256) void k_merge_final(const unsigned* __restrict__ pc,
                                                     const float* __restrict__ vf,
                                                     const float* __restrict__ vm,
                                                     const float* __restrict__ inv_vf_s,
                                                     const float* __restrict__ flow_ws,
                                                     float* __restrict__ out) {
  int T = blockIdx.x * 256 + threadIdx.x;
  int q = T >> 4, c = T & 15, batch = q >> 11;
  if (vm[q] >= 0.5f) return;
  const float4* qp = (const float4*)(vf + (size_t)q * DD);
  float tv[8];
  int ti[8];
#pragma unroll
  for (int k = 0; k < 8; k++) { tv[k] = -3.0e38f; ti[k] = 0; }
  {  // pk <= 0xFFF = masked sentinel, skip
    unsigned pk = pc[(size_t)c * NQ + q];
    if (pk > 0xFFFu) {
      int id = (int)(pk & 0xFFFu);
      int krow = batch * NVV + id;
      float s = dot64(qp, (const float4*)(vf + (size_t)krow * DD)) *
                inv_vf_s[krow] * 6.103515625e-5f;
      ins8(tv, ti, s, id);
    }
  }
#pragma unroll
  for (int m = 1; m <= 8; m <<= 1) {
    float ov[8];
    int oi[8];
#pragma unroll
    for (int k = 0; k < 8; k++) {
      ov[k] = __shfl_xor(tv[k], m, 64);
      oi[k] = __shfl_xor(ti[k], m, 64);
    }
#pragma unroll
    for (int k = 7; k >= 0; k--)
      if (ov[k] > tv[0]) ins8(tv, ti, ov[k], oi[k]);
  }
  int id = ti[0];
  float sv = tv[0];
#pragma unroll
  for (int k = 1; k < 8; k++) {
    id = (c == k) ? ti[k] : id;
    sv = (c == k) ? tv[k] : sv;
  }

  float ax = 0.f, ay = 0.f, az = 0.f, den = 0.f;
  if (c < 8) {
    int krow = batch * NVV + id;
    float w = sv * 16384.0f / inv_vf_s[krow];
    ax = flow_ws[krow * 4 + 0] * w;
    ay = flow_ws[krow * 4 + 1] * w;
    az = flow_ws[krow * 4 + 2] * w;
    den = w;
  }
#pragma unroll
  for (int m = 1; m <= 8; m <<= 1) {
    ax += __shfl_xor(ax, m, 64);
    ay += __shfl_xor(ay, m, 64);
    az += __shfl_xor(az, m, 64);
    den += __shfl_xor(den, m, 64);
  }
  if (c == 0) {
    out[q * 4 + 0] = ax / den;
    out[q * 4 + 1] = ay / den;
    out[q * 4 + 2] = az / den;
  }
}

extern "C" void kernel_launch(void* const* d_in, const int* in_sizes, int n_in,
                              void* d_out, int out_size, void* d_ws, size_t ws_size,
                              hipStream_t stream) {
  const float* vtx = (const float*)d_in[0];
  const float* pts = (const float*)d_in[1];
  const float* vf = (const float*)d_in[2];
  const float* pf = (const float*)d_in[3];
  const float* lg = (const float*)d_in[4];
  float* out = (float*)d_out;
  float* ws = (float*)d_ws;

  float* vm = ws;
  float* inv_vf_s = ws + 16384;
  float* inv_pf_s = ws + 32768;
  float* flow = ws + 65536;
  unsigned* pc1 = (unsigned*)(ws + 131072);
  unsigned* pc2 = (unsigned*)(ws + 393216);
  unsigned short* vfh = (unsigned short*)(ws + 655360);
  unsigned short* vfl = (unsigned short*)(ws + 1179648);   // +524288 floats
  unsigned short* pfh = (unsigned short*)(ws + 1703936);   // +524288
  unsigned short* pfl = (unsigned short*)(ws + 2752512);   // +1048576

  k_prep<<<BB + 768, 256, 0, stream>>>(lg, vf, pf, vm, inv_vf_s, inv_pf_s,
                                       vfh, vfl, pfh, pfl, out);
  k_knn<<<1024, 256, 0, stream>>>(vfh, vfl, pfh, pfl, vm, pc1, pc2);
  k_merge_flow<<<NQ * 16 / 256, 256, 0, stream>>>(pc1, vf, pf, pts, vtx,
                                                  inv_pf_s, flow, out);
  k_merge_final<<<NQ * 16 / 256, 256, 0, stream>>>(pc2, vf, vm, inv_vf_s, flow, out);
}

// Round 8
// 169.733 us; speedup vs baseline: 1.0599x; 1.0292x over previous
//
#include <hip/hip_runtime.h>
#include <math.h>

#define BB 8
#define NVV 2048
#define NPP 4096
#define DD 64
#define NQ (BB * NVV)     // 16384 vertex rows
#define QT (NQ / 16)      // 1024 query tiles

typedef __attribute__((ext_vector_type(8))) short short8;
typedef __attribute__((ext_vector_type(8))) unsigned short ushort8;
typedef __attribute__((ext_vector_type(4))) float f32x4;

// ws layout (float offsets), audited line-by-line (R10 lesson):
// vm      @0        (16384)
// inv_vf_s@16384    (16384)   = 16384/norm
// inv_pf_s@32768    (32768)
// flow    @65536    (65536)
// pc1     @131072   (16*16384 uints = 262144)
// pc2     @393216   (16*16384 uints = 262144)
// vfh     @655360   (QT*1024 ushorts = 524288 floats)
// vfl     @1179648  (+524288)
// pfh     @1703936  (2048 tiles*1024 ushorts = 1048576 floats)
// pfl     @2752512  (+1048576)
// end     @3801088  floats = 14.5 MB

__device__ __forceinline__ unsigned short bf16rn(float x) {
  unsigned u = __float_as_uint(x);
  return (unsigned short)((u + 0x7FFFu + ((u >> 16) & 1u)) >> 16);
}
__device__ __forceinline__ float bf2f(unsigned short h) {
  return __uint_as_float(((unsigned)h) << 16);
}

// Branchless sorted-ascending top-8 insert: 7x v_med3_u32 + 1x max.
__device__ __forceinline__ void net8(unsigned* a, unsigned v) {
#pragma unroll
  for (int k = 0; k < 7; k++) {
    unsigned r;
    asm("v_med3_u32 %0, %1, %2, %3" : "=v"(r) : "v"(v), "v"(a[k]), "v"(a[k + 1]));
    a[k] = r;
  }
  a[7] = a[7] > v ? a[7] : v;
}

// ===== kernel 1: vm (blocks 0..7) + wave-per-tile norm+normalize+staging =====
__global__ __launch_bounds__(256) void k_prep(const float* __restrict__ logits,
                                              const float* __restrict__ vf,
                                              const float* __restrict__ pf,
                                              float* __restrict__ vm,
                                              float* __restrict__ inv_vf_s,
                                              float* __restrict__ inv_pf_s,
                                              unsigned short* __restrict__ vfh,
                                              unsigned short* __restrict__ vfl,
                                              unsigned short* __restrict__ pfh,
                                              unsigned short* __restrict__ pfl,
                                              float* __restrict__ out) {
  int bid = blockIdx.x, t = threadIdx.x;
  if (bid < BB) {
    int b = bid;
    __shared__ float smn[4], smx[4];
    float vals[8];
    float mn = 1e30f, mx = -1e30f;
#pragma unroll
    for (int i = 0; i < 8; i++) {
      float x = logits[b * NVV + t + i * 256];
      float s = 1.0f / (1.0f + expf(-x));
      vals[i] = s;
      mn = fminf(mn, s);
      mx = fmaxf(mx, s);
    }
    for (int o = 32; o; o >>= 1) {
      mn = fminf(mn, __shfl_xor(mn, o, 64));
      mx = fmaxf(mx, __shfl_xor(mx, o, 64));
    }
    int w = t >> 6;
    if ((t & 63) == 0) { smn[w] = mn; smx[w] = mx; }
    __syncthreads();
    mn = fminf(fminf(smn[0], smn[1]), fminf(smn[2], smn[3]));
    mx = fmaxf(fmaxf(smx[0], smx[1]), fmaxf(smx[2], smx[3]));
    float range = mx - mn;
#pragma unroll
    for (int i = 0; i < 8; i++) {
      float v = (vals[i] - mn) / range;
      int g = b * NVV + t + i * 256;
      vm[g] = v;
      out[g * 4 + 3] = v;
    }
  } else {
    // 4 tiles per block (one per wave); 3072 tiles total; vf/pf split at
    // tile 1024 (4-aligned -> no block straddles)
    int tile_g = (bid - BB) * 4 + (t >> 6);
    int lane = t & 63, c = lane & 15, quad = (lane >> 4) & 3;
    const float* src;
    unsigned short *dh, *dl;
    float* ginv;
    int tile;
    if (tile_g < QT) { tile = tile_g; src = vf; dh = vfh; dl = vfl; ginv = inv_vf_s; }
    else { tile = tile_g - QT; src = pf; dh = pfh; dl = pfl; ginv = inv_pf_s; }
    int row = tile * 16 + c;
    const float* rp = src + (size_t)row * DD + quad * 8;
    float4 a0 = *(const float4*)(rp);
    float4 b0 = *(const float4*)(rp + 4);
    float4 a1 = *(const float4*)(rp + 32);
    float4 b1 = *(const float4*)(rp + 36);
    float xs[16] = {a0.x, a0.y, a0.z, a0.w, b0.x, b0.y, b0.z, b0.w,
                    a1.x, a1.y, a1.z, a1.w, b1.x, b1.y, b1.z, b1.w};
    float ss = 0.f;
#pragma unroll
    for (int j = 0; j < 16; j++) ss = fmaf(xs[j], xs[j], ss);
    ss += __shfl_xor(ss, 16, 64);
    ss += __shfl_xor(ss, 32, 64);   // all quads now hold the row total
    float inv = 1.0f / fmaxf(sqrtf(ss), 1e-12f);
    if (quad == 0) ginv[row] = 16384.0f * inv;  // pow2 scale: exact ratio later
    ushort8 h, l;
    size_t s0 = (size_t)tile * 128 + lane;      // kk=0 slot
#pragma unroll
    for (int j = 0; j < 8; j++) {
      float xn = xs[j] * inv;
      unsigned short hj = bf16rn(xn);
      h[j] = hj;
      l[j] = bf16rn(xn - bf2f(hj));
    }
    *(ushort8*)(dh + s0 * 8) = h;
    *(ushort8*)(dl + s0 * 8) = l;
#pragma unroll
    for (int j = 0; j < 8; j++) {
      float xn = xs[8 + j] * inv;
      unsigned short hj = bf16rn(xn);
      h[j] = hj;
      l[j] = bf16rn(xn - bf2f(hj));
    }
    *(ushort8*)(dh + (s0 + 64) * 8) = h;      // kk=1 slot
    *(ushort8*)(dl + (s0 + 64) * 8) = l;
  }
}

// ===== kernel 2: MFMA KNN candidate generation (fused KNN1 + KNN2) =====
// R20 version (kept): 2-deep register software-pipeline + split top-8
// chains (tvA r=0,1 / tvB r=2,3, exact union-merge). R19 balanced
// schedule, XCD batch-pinning, LDS half-pair union-merge. 77 us; five
// rounds of levers say this is within ~10% of its structural VALU floor.

#define LOADK(d0, d1, d2, d3, KH, KL, tile) do {            \
    size_t bo_ = (size_t)(tile) * 1024 + lane * 8;          \
    d0 = *(const short8*)((KH) + bo_);                      \
    d1 = *(const short8*)((KH) + bo_ + 512);                \
    d2 = *(const short8*)((KL) + bo_);                      \
    d3 = *(const short8*)((KL) + bo_ + 512);                \
  } while (0)

#define MFMA6(c_, h0_, h1_, l0_, l1_) do {                                  \
    c_ = __builtin_amdgcn_mfma_f32_16x16x32_bf16(h0_, qh0, c_, 0, 0, 0);    \
    c_ = __builtin_amdgcn_mfma_f32_16x16x32_bf16(h1_, qh1, c_, 0, 0, 0);    \
    c_ = __builtin_amdgcn_mfma_f32_16x16x32_bf16(h0_, ql0, c_, 0, 0, 0);    \
    c_ = __builtin_amdgcn_mfma_f32_16x16x32_bf16(h1_, ql1, c_, 0, 0, 0);    \
    c_ = __builtin_amdgcn_mfma_f32_16x16x32_bf16(l0_, qh0, c_, 0, 0, 0);    \
    c_ = __builtin_amdgcn_mfma_f32_16x16x32_bf16(l1_, qh1, c_, 0, 0, 0);    \
  } while (0)

#define COMP1(h0_, h1_, l0_, l1_, b16_) do {                                \
    f32x4 c_ = {0.f, 0.f, 0.f, 0.f};                                        \
    MFMA6(c_, h0_, h1_, l0_, l1_);                                          \
    unsigned u0_ = (unsigned)fmaxf(fmaf(c_[0], 520000.0f, 520000.0f), 0.0f);\
    net8(tvA, (u0_ << 12) | (unsigned)((b16_) + 0));                        \
    unsigned u1_ = (unsigned)fmaxf(fmaf(c_[1], 520000.0f, 520000.0f), 0.0f);\
    net8(tvA, (u1_ << 12) | (unsigned)((b16_) + 1));                        \
    unsigned u2_ = (unsigned)fmaxf(fmaf(c_[2], 520000.0f, 520000.0f), 0.0f);\
    net8(tvB, (u2_ << 12) | (unsigned)((b16_) + 2));                        \
    unsigned u3_ = (unsigned)fmaxf(fmaf(c_[3], 520000.0f, 520000.0f), 0.0f);\
    net8(tvB, (u3_ << 12) | (unsigned)((b16_) + 3));                        \
  } while (0)

#define COMP2(h0_, h1_, l0_, l1_, b16_, mp_) do {                           \
    float4 mv_ = *(const float4*)(mp_);                                     \
    f32x4 c_ = {0.f, 0.f, 0.f, 0.f};                                        \
    MFMA6(c_, h0_, h1_, l0_, l1_);                                          \
    unsigned u0_ = (unsigned)fmaxf(fmaf(c_[0], 520000.0f, 520000.0f), 0.0f);\
    unsigned p0_ = (u0_ << 12) | (unsigned)((b16_) + 0);                    \
    net8(tvA, (mv_.x >= 0.5f) ? p0_ : 0u);                                  \
    unsigned u1_ = (unsigned)fmaxf(fmaf(c_[1], 520000.0f, 520000.0f), 0.0f);\
    unsigned p1_ = (u1_ << 12) | (unsigned)((b16_) + 1);                    \
    net8(tvA, (mv_.y >= 0.5f) ? p1_ : 0u);                                  \
    unsigned u2_ = (unsigned)fmaxf(fmaf(c_[2], 520000.0f, 520000.0f), 0.0f);\
    unsigned p2_ = (u2_ << 12) | (unsigned)((b16_) + 2);                    \
    net8(tvB, (mv_.z >= 0.5f) ? p2_ : 0u);                                  \
    unsigned u3_ = (unsigned)fmaxf(fmaf(c_[3], 520000.0f, 520000.0f), 0.0f);\
    unsigned p3_ = (u3_ << 12) | (unsigned)((b16_) + 3);                    \
    net8(tvB, (mv_.w >= 0.5f) ? p3_ : 0u);                                  \
  } while (0)

__global__ __launch_bounds__(256)
void k_knn(const unsigned short* __restrict__ vfh, const unsigned short* __restrict__ vfl,
           const unsigned short* __restrict__ pfh, const unsigned short* __restrict__ pfl,
           const float* __restrict__ vm,
           unsigned* __restrict__ pc1, unsigned* __restrict__ pc2) {
  __shared__ unsigned mg[2][2][16][8];   // [section][ck][col][k]

  int p = blockIdx.x;                 // 0..1023
  int xcd = p & 7, j = p >> 3;        // batch pin: batch == xcd
  int qt_g = xcd * 128 + j;           // this block's query tile
  int batch = xcd;
  int w = (int)threadIdx.x >> 6;      // wave 0..3
  int ck = w >> 1, hf = w & 1;        // chunk, half within chunk
  int lane = threadIdx.x & 63, col = lane & 15, quad = lane >> 4;

  // query frags once per wave (serve both phases)
  size_t ab = (size_t)qt_g * 1024 + lane * 8;
  short8 qh0 = *(const short8*)(vfh + ab);
  short8 qh1 = *(const short8*)(vfh + ab + 512);
  short8 ql0 = *(const short8*)(vfl + ab);
  short8 ql1 = *(const short8*)(vfl + ab + 512);
  // Pin loop-invariant query frags in AGPRs: MFMA reads AGPR A/B natively.
  asm volatile("" : "+a"(qh0), "+a"(qh1), "+a"(ql0), "+a"(ql1));

  unsigned tvA[8], tvB[8];

  // ---------------- phase A: KNN1 (keys = pf), 64 tiles ----------------
#pragma unroll
  for (int k = 0; k < 8; k++) { tvA[k] = 0u; tvB[k] = 0u; }
  {
    int bt0 = batch * 256 + ck * 128 + hf * 64;
    int tb16 = (ck * 128 + hf * 64) * 16 + quad * 4;
    short8 ah0, ah1, al0, al1, bh0, bh1, bl0, bl1;
    LOADK(ah0, ah1, al0, al1, pfh, pfl, bt0);
#pragma unroll 1
    for (int kt = 0; kt < 62; kt += 2) {
      LOADK(bh0, bh1, bl0, bl1, pfh, pfl, bt0 + kt + 1);
      COMP1(ah0, ah1, al0, al1, tb16 + kt * 16);
      LOADK(ah0, ah1, al0, al1, pfh, pfl, bt0 + kt + 2);
      COMP1(bh0, bh1, bl0, bl1, tb16 + (kt + 1) * 16);
    }
    LOADK(bh0, bh1, bl0, bl1, pfh, pfl, bt0 + 63);
    COMP1(ah0, ah1, al0, al1, tb16 + 62 * 16);
    COMP1(bh0, bh1, bl0, bl1, tb16 + 63 * 16);
  }
  // exact union of the two chains
#pragma unroll
  for (int k = 0; k < 8; k++) net8(tvA, tvB[k]);
  // butterfly across quads (lane bits 4,5) -- all quads end identical
#pragma unroll
  for (int m = 16; m <= 32; m <<= 1) {
    unsigned ov[8];
#pragma unroll
    for (int k = 0; k < 8; k++) ov[k] = (unsigned)__shfl_xor((int)tvA[k], m, 64);
#pragma unroll
    for (int k = 7; k >= 0; k--) net8(tvA, ov[k]);
  }
  if (hf == 1 && quad == 0) {
#pragma unroll
    for (int k = 0; k < 8; k++) mg[0][ck][col][k] = tvA[k];
  }
  __syncthreads();
  if (hf == 0 && quad == 0) {
#pragma unroll
    for (int k = 0; k < 8; k++) net8(tvA, mg[0][ck][col][k]);
    int q = qt_g * 16 + col;
#pragma unroll
    for (int k = 0; k < 8; k++)
      pc1[(size_t)(ck * 8 + k) * NQ + q] = tvA[k];
  }

  // ---------------- phase B: KNN2 (keys = vf, visible only), 32 tiles ----
#pragma unroll
  for (int k = 0; k < 8; k++) { tvA[k] = 0u; tvB[k] = 0u; }
  {
    const float* mask = vm + batch * NVV;
    int bt0 = batch * 128 + ck * 64 + hf * 32;
    int tbase = ck * 64 + hf * 32;
    int tb16 = tbase * 16 + quad * 4;
    const float* mp0 = mask + tbase * 16 + quad * 4;
    short8 ah0, ah1, al0, al1, bh0, bh1, bl0, bl1;
    LOADK(ah0, ah1, al0, al1, vfh, vfl, bt0);
#pragma unroll 1
    for (int kt = 0; kt < 30; kt += 2) {
      LOADK(bh0, bh1, bl0, bl1, vfh, vfl, bt0 + kt + 1);
      COMP2(ah0, ah1, al0, al1, tb16 + kt * 16, mp0 + kt * 16);
      LOADK(ah0, ah1, al0, al1, vfh, vfl, bt0 + kt + 2);
      COMP2(bh0, bh1, bl0, bl1, tb16 + (kt + 1) * 16, mp0 + (kt + 1) * 16);
    }
    LOADK(bh0, bh1, bl0, bl1, vfh, vfl, bt0 + 31);
    COMP2(ah0, ah1, al0, al1, tb16 + 30 * 16, mp0 + 30 * 16);
    COMP2(bh0, bh1, bl0, bl1, tb16 + 31 * 16, mp0 + 31 * 16);
  }
#pragma unroll
  for (int k = 0; k < 8; k++) net8(tvA, tvB[k]);
#pragma unroll
  for (int m = 16; m <= 32; m <<= 1) {
    unsigned ov[8];
#pragma unroll
    for (int k = 0; k < 8; k++) ov[k] = (unsigned)__shfl_xor((int)tvA[k], m, 64);
#pragma unroll
    for (int k = 7; k >= 0; k--) net8(tvA, ov[k]);
  }
  if (hf == 1 && quad == 0) {
#pragma unroll
    for (int k = 0; k < 8; k++) mg[1][ck][col][k] = tvA[k];
  }
  __syncthreads();
  if (hf == 0 && quad == 0) {
#pragma unroll
    for (int k = 0; k < 8; k++) net8(tvA, mg[1][ck][col][k]);
    int q = qt_g * 16 + col;
#pragma unroll
    for (int k = 0; k < 8; k++)
      pc2[(size_t)(ck * 8 + k) * NQ + q] = tvA[k];
  }
}

__device__ __forceinline__ float dot64(const float4* __restrict__ a,
                                       const float4* __restrict__ b) {
  float a0 = 0.f, a1 = 0.f, a2 = 0.f, a3 = 0.f;
#pragma unroll
  for (int c = 0; c < 16; c++) {
    float4 x = a[c], y = b[c];
    a0 = fmaf(x.x, y.x, a0);
    a1 = fmaf(x.y, y.y, a1);
    a2 = fmaf(x.z, y.z, a2);
    a3 = fmaf(x.w, y.w, a3);
  }
  return (a0 + a1) + (a2 + a3);
}

// sortable u32 from fp32: monotone bijection (total order preserved)
__device__ __forceinline__ unsigned fkey(float s) {
  unsigned u = __float_as_uint(s);
  return ((int)u < 0) ? ~u : (u | 0x80000000u);
}

// ===== kernel 3: exact re-rank of 16 KNN1 candidates + flow_init =====
// R21: replaced the divergent ins8 butterfly (~1000+ VALU/thread, 8
// branchy inserts x 4 stages) with exact rank-selection: sortable-u32 of
// the exact fp32 cosine, 16-step shfl rank loop (tie-break by id; ids
// distinct across the two disjoint chunks), rank<8 <=> exact top-8 set.
// Straight-line ~175 VALU. Weights use raw dot directly (bit-closer to
// reference than the old scale/unscale). XCD batch-pinning added (R17
// mechanism): per-XCD candidate rows = 1 MB pf -> L2-resident.
__global__ __launch_bounds__(256) void k_merge_flow(const unsigned* __restrict__ pc,
                                                    const float* __restrict__ vf,
                                                    const float* __restrict__ pf,
                                                    const float* __restrict__ pts,
                                                    const float* __restrict__ vtx,
                                                    const float* __restrict__ inv_pf_s,
                                                    float* __restrict__ flow_ws,
                                                    float* __restrict__ out) {
  int p = blockIdx.x;
  int xcd = p & 7, jj = p >> 3;
  int lb = xcd * 128 + jj;            // batch == lb>>7 == xcd
  int T = lb * 256 + (int)threadIdx.x;
  int q = T >> 4, c = T & 15, batch = q >> 11;
  int lane = (int)threadIdx.x & 63;
  int base = lane & 48;               // start lane of my 16-group

  unsigned pk = pc[(size_t)c * NQ + q];
  int id = (int)(pk & 0xFFFu);
  int prow = batch * NPP + id;
  const float4* qp = (const float4*)(vf + (size_t)q * DD);
  float dot = dot64(qp, (const float4*)(pf + (size_t)prow * DD));
  float s = dot * inv_pf_s[prow];     // exact cosine * 2^14 (uniform pow2 scale)
  unsigned kb = fkey(s);

  int rank = 0;
#pragma unroll
  for (int i = 0; i < 16; i++) {
    unsigned ok = (unsigned)__shfl((int)kb, base + i, 64);
    int oid = __shfl(id, base + i, 64);
    rank += (ok > kb || (ok == kb && oid > id)) ? 1 : 0;
  }
  float wgt = (rank < 8) ? dot : 0.0f;  // raw dot weight (vm[q] cancels)

  float ax = (pts[prow * 3 + 0] - vtx[q * 3 + 0]) * wgt;
  float ay = (pts[prow * 3 + 1] - vtx[q * 3 + 1]) * wgt;
  float az = (pts[prow * 3 + 2] - vtx[q * 3 + 2]) * wgt;
  float den = wgt;
#pragma unroll
  for (int m = 1; m <= 8; m <<= 1) {
    ax += __shfl_xor(ax, m, 64);
    ay += __shfl_xor(ay, m, 64);
    az += __shfl_xor(az, m, 64);
    den += __shfl_xor(den, m, 64);
  }
  if (c == 0) {
    float fx = ax / den, fy = ay / den, fz = az / den;
    flow_ws[q * 4 + 0] = fx;
    flow_ws[q * 4 + 1] = fy;
    flow_ws[q * 4 + 2] = fz;
    out[q * 4 + 0] = fx;
    out[q * 4 + 1] = fy;
    out[q * 4 + 2] = fz;
  }
}

// ===== kernel 4: exact re-rank of 16 KNN2 candidates + interpolate invisible =====
// R21: same rank-selection rewrite + XCD pinning as k_merge_flow.
__global__ __launch_bounds__(256) void k_merge_final(const unsigned* __restrict__ pc,
                                                     const float* __restrict__ vf,
                                                     const float* __restrict__ vm,
                                                     const float* __restrict__ inv_vf_s,
                                                     const float* __restrict__ flow_ws,
                                                     float* __restrict__ out) {
  int p = blockIdx.x;
  int xcd = p & 7, jj = p >> 3;
  int lb = xcd * 128 + jj;            // batch == xcd
  int T = lb * 256 + (int)threadIdx.x;
  int q = T >> 4, c = T & 15, batch = q >> 11;
  if (vm[q] >= 0.5f) return;          // whole 16-group exits together
  int lane = (int)threadIdx.x & 63;
  int base = lane & 48;

  unsigned pk = pc[(size_t)c * NQ + q];
  bool valid = pk > 0xFFFu;           // 0 = masked sentinel
  int id = (int)(pk & 0xFFFu);
  int krow = batch * NVV + id;
  const float4* qp = (const float4*)(vf + (size_t)q * DD);
  float dot = dot64(qp, (const float4*)(vf + (size_t)krow * DD));
  float s = dot * inv_vf_s[krow];
  unsigned kb = valid ? fkey(s) : 0u;

  int rank = 0;
#pragma unroll
  for (int i = 0; i < 16; i++) {
    unsigned ok = (unsigned)__shfl((int)kb, base + i, 64);
    int oid = __shfl(id, base + i, 64);
    rank += (ok > kb || (ok == kb && oid > id)) ? 1 : 0;
  }
  float wgt = (valid && rank < 8) ? dot : 0.0f;

  float ax = flow_ws[krow * 4 + 0] * wgt;
  float ay = flow_ws[krow * 4 + 1] * wgt;
  float az = flow_ws[krow * 4 + 2] * wgt;
  float den = wgt;
#pragma unroll
  for (int m = 1; m <= 8; m <<= 1) {
    ax += __shfl_xor(ax, m, 64);
    ay += __shfl_xor(ay, m, 64);
    az += __shfl_xor(az, m, 64);
    den += __shfl_xor(den, m, 64);
  }
  if (c == 0) {
    out[q * 4 + 0] = ax / den;
    out[q * 4 + 1] = ay / den;
    out[q * 4 + 2] = az / den;
  }
}

extern "C" void kernel_launch(void* const* d_in, const int* in_sizes, int n_in,
                              void* d_out, int out_size, void* d_ws, size_t ws_size,
                              hipStream_t stream) {
  const float* vtx = (const float*)d_in[0];
  const float* pts = (const float*)d_in[1];
  const float* vf = (const float*)d_in[2];
  const float* pf = (const float*)d_in[3];
  const float* lg = (const float*)d_in[4];
  float* out = (float*)d_out;
  float* ws = (float*)d_ws;

  float* vm = ws;
  float* inv_vf_s = ws + 16384;
  float* inv_pf_s = ws + 32768;
  float* flow = ws + 65536;
  unsigned* pc1 = (unsigned*)(ws + 131072);
  unsigned* pc2 = (unsigned*)(ws + 393216);
  unsigned short* vfh = (unsigned short*)(ws + 655360);
  unsigned short* vfl = (unsigned short*)(ws + 1179648);   // +524288 floats
  unsigned short* pfh = (unsigned short*)(ws + 1703936);   // +524288
  unsigned short* pfl = (unsigned short*)(ws + 2752512);   // +1048576

  k_prep<<<BB + 768, 256, 0, stream>>>(lg, vf, pf, vm, inv_vf_s, inv_pf_s,
                                       vfh, vfl, pfh, pfl, out);
  k_knn<<<1024, 256, 0, stream>>>(vfh, vfl, pfh, pfl, vm, pc1, pc2);
  k_merge_flow<<<NQ * 16 / 256, 256, 0, stream>>>(pc1, vf, pf, pts, vtx,
                                                  inv_pf_s, flow, out);
  k_merge_final<<<NQ * 16 / 256, 256, 0, stream>>>(pc2, vf, vm, inv_vf_s, flow, out);
}

// Round 10
// 163.888 us; speedup vs baseline: 1.0977x; 1.0357x over previous
//
#include <hip/hip_runtime.h>
#include <math.h>

#define BB 8
#define NVV 2048
#define NPP 4096
#define DD 64
#define NQ (BB * NVV)     // 16384 vertex rows
#define QT (NQ / 16)      // 1024 query tiles

typedef __attribute__((ext_vector_type(8))) short short8;
typedef __attribute__((ext_vector_type(8))) unsigned short ushort8;
typedef __attribute__((ext_vector_type(4))) float f32x4;

// ws layout (float offsets), audited line-by-line (R10 lesson):
// vm      @0        (16384)
// inv_vf_s@16384    (16384)   = 16384/norm
// inv_pf_s@32768    (32768)
// flow    @65536    (65536)
// pc1     @131072   (unused since R23 fold; layout kept)
// pc2     @393216   (16*16384 uints = 262144)
// vfh     @655360   (QT*1024 ushorts = 524288 floats)
// vfl     @1179648  (+524288)
// pfh     @1703936  (2048 tiles*1024 ushorts = 1048576 floats)
// pfl     @2752512  (+1048576)
// end     @3801088  floats = 14.5 MB

__device__ __forceinline__ unsigned short bf16rn(float x) {
  unsigned u = __float_as_uint(x);
  return (unsigned short)((u + 0x7FFFu + ((u >> 16) & 1u)) >> 16);
}
__device__ __forceinline__ float bf2f(unsigned short h) {
  return __uint_as_float(((unsigned)h) << 16);
}

// Branchless sorted-ascending top-8 insert: 7x v_med3_u32 + 1x max.
__device__ __forceinline__ void net8(unsigned* a, unsigned v) {
#pragma unroll
  for (int k = 0; k < 7; k++) {
    unsigned r;
    asm("v_med3_u32 %0, %1, %2, %3" : "=v"(r) : "v"(v), "v"(a[k]), "v"(a[k + 1]));
    a[k] = r;
  }
  a[7] = a[7] > v ? a[7] : v;
}

__device__ __forceinline__ float dot64(const float4* __restrict__ a,
                                       const float4* __restrict__ b) {
  float a0 = 0.f, a1 = 0.f, a2 = 0.f, a3 = 0.f;
#pragma unroll
  for (int c = 0; c < 16; c++) {
    float4 x = a[c], y = b[c];
    a0 = fmaf(x.x, y.x, a0);
    a1 = fmaf(x.y, y.y, a1);
    a2 = fmaf(x.z, y.z, a2);
    a3 = fmaf(x.w, y.w, a3);
  }
  return (a0 + a1) + (a2 + a3);
}

// sortable u32 from fp32: monotone bijection (total order preserved)
__device__ __forceinline__ unsigned fkey(float s) {
  unsigned u = __float_as_uint(s);
  return ((int)u < 0) ? ~u : (u | 0x80000000u);
}

// ===== kernel 1: vm (blocks 0..7) + wave-per-tile norm+normalize+staging =====
__global__ __launch_bounds__(256) void k_prep(const float* __restrict__ logits,
                                              const float* __restrict__ vf,
                                              const float* __restrict__ pf,
                                              float* __restrict__ vm,
                                              float* __restrict__ inv_vf_s,
                                              float* __restrict__ inv_pf_s,
                                              unsigned short* __restrict__ vfh,
                                              unsigned short* __restrict__ vfl,
                                              unsigned short* __restrict__ pfh,
                                              unsigned short* __restrict__ pfl,
                                              float* __restrict__ out) {
  int bid = blockIdx.x, t = threadIdx.x;
  if (bid < BB) {
    int b = bid;
    __shared__ float smn[4], smx[4];
    float vals[8];
    float mn = 1e30f, mx = -1e30f;
#pragma unroll
    for (int i = 0; i < 8; i++) {
      float x = logits[b * NVV + t + i * 256];
      float s = 1.0f / (1.0f + expf(-x));
      vals[i] = s;
      mn = fminf(mn, s);
      mx = fmaxf(mx, s);
    }
    for (int o = 32; o; o >>= 1) {
      mn = fminf(mn, __shfl_xor(mn, o, 64));
      mx = fmaxf(mx, __shfl_xor(mx, o, 64));
    }
    int w = t >> 6;
    if ((t & 63) == 0) { smn[w] = mn; smx[w] = mx; }
    __syncthreads();
    mn = fminf(fminf(smn[0], smn[1]), fminf(smn[2], smn[3]));
    mx = fmaxf(fmaxf(smx[0], smx[1]), fmaxf(smx[2], smx[3]));
    float range = mx - mn;
#pragma unroll
    for (int i = 0; i < 8; i++) {
      float v = (vals[i] - mn) / range;
      int g = b * NVV + t + i * 256;
      vm[g] = v;
      out[g * 4 + 3] = v;
    }
  } else {
    // 4 tiles per block (one per wave); 3072 tiles total; vf/pf split at
    // tile 1024 (4-aligned -> no block straddles)
    int tile_g = (bid - BB) * 4 + (t >> 6);
    int lane = t & 63, c = lane & 15, quad = (lane >> 4) & 3;
    const float* src;
    unsigned short *dh, *dl;
    float* ginv;
    int tile;
    if (tile_g < QT) { tile = tile_g; src = vf; dh = vfh; dl = vfl; ginv = inv_vf_s; }
    else { tile = tile_g - QT; src = pf; dh = pfh; dl = pfl; ginv = inv_pf_s; }
    int row = tile * 16 + c;
    const float* rp = src + (size_t)row * DD + quad * 8;
    float4 a0 = *(const float4*)(rp);
    float4 b0 = *(const float4*)(rp + 4);
    float4 a1 = *(const float4*)(rp + 32);
    float4 b1 = *(const float4*)(rp + 36);
    float xs[16] = {a0.x, a0.y, a0.z, a0.w, b0.x, b0.y, b0.z, b0.w,
                    a1.x, a1.y, a1.z, a1.w, b1.x, b1.y, b1.z, b1.w};
    float ss = 0.f;
#pragma unroll
    for (int j = 0; j < 16; j++) ss = fmaf(xs[j], xs[j], ss);
    ss += __shfl_xor(ss, 16, 64);
    ss += __shfl_xor(ss, 32, 64);   // all quads now hold the row total
    float inv = 1.0f / fmaxf(sqrtf(ss), 1e-12f);
    if (quad == 0) ginv[row] = 16384.0f * inv;  // pow2 scale: exact ratio later
    ushort8 h, l;
    size_t s0 = (size_t)tile * 128 + lane;      // kk=0 slot
#pragma unroll
    for (int j = 0; j < 8; j++) {
      float xn = xs[j] * inv;
      unsigned short hj = bf16rn(xn);
      h[j] = hj;
      l[j] = bf16rn(xn - bf2f(hj));
    }
    *(ushort8*)(dh + s0 * 8) = h;
    *(ushort8*)(dl + s0 * 8) = l;
#pragma unroll
    for (int j = 0; j < 8; j++) {
      float xn = xs[8 + j] * inv;
      unsigned short hj = bf16rn(xn);
      h[j] = hj;
      l[j] = bf16rn(xn - bf2f(hj));
    }
    *(ushort8*)(dh + (s0 + 64) * 8) = h;      // kk=1 slot
    *(ushort8*)(dl + (s0 + 64) * 8) = l;
  }
}

// R20 k_knn inner-loop machinery (kept verbatim)
#define LOADK(d0, d1, d2, d3, KH, KL, tile) do {            \
    size_t bo_ = (size_t)(tile) * 1024 + lane * 8;          \
    d0 = *(const short8*)((KH) + bo_);                      \
    d1 = *(const short8*)((KH) + bo_ + 512);                \
    d2 = *(const short8*)((KL) + bo_);                      \
    d3 = *(const short8*)((KL) + bo_ + 512);                \
  } while (0)

#define MFMA6(c_, h0_, h1_, l0_, l1_) do {                                  \
    c_ = __builtin_amdgcn_mfma_f32_16x16x32_bf16(h0_, qh0, c_, 0, 0, 0);    \
    c_ = __builtin_amdgcn_mfma_f32_16x16x32_bf16(h1_, qh1, c_, 0, 0, 0);    \
    c_ = __builtin_amdgcn_mfma_f32_16x16x32_bf16(h0_, ql0, c_, 0, 0, 0);    \
    c_ = __builtin_amdgcn_mfma_f32_16x16x32_bf16(h1_, ql1, c_, 0, 0, 0);    \
    c_ = __builtin_amdgcn_mfma_f32_16x16x32_bf16(l0_, qh0, c_, 0, 0, 0);    \
    c_ = __builtin_amdgcn_mfma_f32_16x16x32_bf16(l1_, qh1, c_, 0, 0, 0);    \
  } while (0)

#define COMP1(h0_, h1_, l0_, l1_, b16_) do {                                \
    f32x4 c_ = {0.f, 0.f, 0.f, 0.f};                                        \
    MFMA6(c_, h0_, h1_, l0_, l1_);                                          \
    unsigned u0_ = (unsigned)fmaxf(fmaf(c_[0], 520000.0f, 520000.0f), 0.0f);\
    net8(tvA, (u0_ << 12) | (unsigned)((b16_) + 0));                        \
    unsigned u1_ = (unsigned)fmaxf(fmaf(c_[1], 520000.0f, 520000.0f), 0.0f);\
    net8(tvA, (u1_ << 12) | (unsigned)((b16_) + 1));                        \
    unsigned u2_ = (unsigned)fmaxf(fmaf(c_[2], 520000.0f, 520000.0f), 0.0f);\
    net8(tvB, (u2_ << 12) | (unsigned)((b16_) + 2));                        \
    unsigned u3_ = (unsigned)fmaxf(fmaf(c_[3], 520000.0f, 520000.0f), 0.0f);\
    net8(tvB, (u3_ << 12) | (unsigned)((b16_) + 3));                        \
  } while (0)

#define COMP2(h0_, h1_, l0_, l1_, b16_, mp_) do {                           \
    float4 mv_ = *(const float4*)(mp_);                                     \
    f32x4 c_ = {0.f, 0.f, 0.f, 0.f};                                        \
    MFMA6(c_, h0_, h1_, l0_, l1_);                                          \
    unsigned u0_ = (unsigned)fmaxf(fmaf(c_[0], 520000.0f, 520000.0f), 0.0f);\
    unsigned p0_ = (u0_ << 12) | (unsigned)((b16_) + 0);                    \
    net8(tvA, (mv_.x >= 0.5f) ? p0_ : 0u);                                  \
    unsigned u1_ = (unsigned)fmaxf(fmaf(c_[1], 520000.0f, 520000.0f), 0.0f);\
    unsigned p1_ = (u1_ << 12) | (unsigned)((b16_) + 1);                    \
    net8(tvA, (mv_.y >= 0.5f) ? p1_ : 0u);                                  \
    unsigned u2_ = (unsigned)fmaxf(fmaf(c_[2], 520000.0f, 520000.0f), 0.0f);\
    unsigned p2_ = (u2_ << 12) | (unsigned)((b16_) + 2);                    \
    net8(tvB, (mv_.z >= 0.5f) ? p2_ : 0u);                                  \
    unsigned u3_ = (unsigned)fmaxf(fmaf(c_[3], 520000.0f, 520000.0f), 0.0f);\
    unsigned p3_ = (u3_ << 12) | (unsigned)((b16_) + 3);                    \
    net8(tvB, (mv_.w >= 0.5f) ? p3_ : 0u);                                  \
  } while (0)

// ===== kernel 2: MFMA KNN + FUSED exact KNN1 re-rank & flow (R23) =====
// R22 post-mortem: cooperative launch no-ops under hipGraph capture (all-
// zero output) -> reverted. R23 keeps the fusion idea where NO grid sync
// is needed: pc1 for tile qt_g is produced entirely inside block p (both
// chunks, union-merged in LDS), and the re-rank is exactly 256 dot64s =
// one per thread. Fold k_merge_flow in as an epilogue after phase A:
// finished top-8 lists -> cand[16][16] LDS -> R21 rank-selection body
// verbatim (pc1 load replaced by LDS read). Deletes one kernel launch,
// the pc1 global round-trip, and re-reads pf rows while L2-hot.
// k_merge_final stays separate (gathers flow_ws from other blocks ->
// needs the kernel-boundary fence). Math bit-identical to R21.
__global__ __launch_bounds__(256)
void k_knn(const unsigned short* __restrict__ vfh, const unsigned short* __restrict__ vfl,
           const unsigned short* __restrict__ pfh, const unsigned short* __restrict__ pfl,
           const float* __restrict__ vm, unsigned* __restrict__ pc2,
           const float* __restrict__ vf, const float* __restrict__ pf,
           const float* __restrict__ pts, const float* __restrict__ vtx,
           const float* __restrict__ inv_pf_s,
           float* __restrict__ flow_ws, float* __restrict__ out) {
  __shared__ unsigned mg[2][2][16][8];   // [section][ck][col][k]
  __shared__ unsigned cand[16][16];      // [q-in-tile][candidate]

  int p = blockIdx.x;                 // 0..1023
  int xcd = p & 7, j = p >> 3;        // batch pin: batch == xcd
  int qt_g = xcd * 128 + j;           // this block's query tile
  int batch = xcd;
  int w = (int)threadIdx.x >> 6;      // wave 0..3
  int ck = w >> 1, hf = w & 1;        // chunk, half within chunk
  int lane = threadIdx.x & 63, col = lane & 15, quad = lane >> 4;

  // query frags once per wave (serve both phases)
  size_t ab = (size_t)qt_g * 1024 + lane * 8;
  short8 qh0 = *(const short8*)(vfh + ab);
  short8 qh1 = *(const short8*)(vfh + ab + 512);
  short8 ql0 = *(const short8*)(vfl + ab);
  short8 ql1 = *(const short8*)(vfl + ab + 512);
  // Pin loop-invariant query frags in AGPRs: MFMA reads AGPR A/B natively.
  asm volatile("" : "+a"(qh0), "+a"(qh1), "+a"(ql0), "+a"(ql1));

  unsigned tvA[8], tvB[8];

  // ---------------- phase A: KNN1 (keys = pf), 64 tiles ----------------
#pragma unroll
  for (int k = 0; k < 8; k++) { tvA[k] = 0u; tvB[k] = 0u; }
  {
    int bt0 = batch * 256 + ck * 128 + hf * 64;
    int tb16 = (ck * 128 + hf * 64) * 16 + quad * 4;
    short8 ah0, ah1, al0, al1, bh0, bh1, bl0, bl1;
    LOADK(ah0, ah1, al0, al1, pfh, pfl, bt0);
#pragma unroll 1
    for (int kt = 0; kt < 62; kt += 2) {
      LOADK(bh0, bh1, bl0, bl1, pfh, pfl, bt0 + kt + 1);
      COMP1(ah0, ah1, al0, al1, tb16 + kt * 16);
      LOADK(ah0, ah1, al0, al1, pfh, pfl, bt0 + kt + 2);
      COMP1(bh0, bh1, bl0, bl1, tb16 + (kt + 1) * 16);
    }
    LOADK(bh0, bh1, bl0, bl1, pfh, pfl, bt0 + 63);
    COMP1(ah0, ah1, al0, al1, tb16 + 62 * 16);
    COMP1(bh0, bh1, bl0, bl1, tb16 + 63 * 16);
  }
  // exact union of the two chains
#pragma unroll
  for (int k = 0; k < 8; k++) net8(tvA, tvB[k]);
  // butterfly across quads (lane bits 4,5) -- all quads end identical
#pragma unroll
  for (int m = 16; m <= 32; m <<= 1) {
    unsigned ov[8];
#pragma unroll
    for (int k = 0; k < 8; k++) ov[k] = (unsigned)__shfl_xor((int)tvA[k], m, 64);
#pragma unroll
    for (int k = 7; k >= 0; k--) net8(tvA, ov[k]);
  }
  if (hf == 1 && quad == 0) {
#pragma unroll
    for (int k = 0; k < 8; k++) mg[0][ck][col][k] = tvA[k];
  }
  __syncthreads();
  if (hf == 0 && quad == 0) {
#pragma unroll
    for (int k = 0; k < 8; k++) net8(tvA, mg[0][ck][col][k]);
#pragma unroll
    for (int k = 0; k < 8; k++)
      cand[col][ck * 8 + k] = tvA[k];
  }
  __syncthreads();

  // ------- fused exact re-rank of 16 KNN1 candidates + flow (R21 body) -------
  {
    int t = (int)threadIdx.x;
    int qloc = t >> 4, c = t & 15;
    int q = qt_g * 16 + qloc;
    int base = lane & 48;               // 16-lane group start (same as R21)

    unsigned pk = cand[qloc][c];
    int id = (int)(pk & 0xFFFu);
    int prow = batch * NPP + id;
    const float4* qp = (const float4*)(vf + (size_t)q * DD);
    float dotv = dot64(qp, (const float4*)(pf + (size_t)prow * DD));
    float s = dotv * inv_pf_s[prow];    // exact cosine * 2^14 (uniform pow2 scale)
    unsigned kb = fkey(s);

    int rank = 0;
#pragma unroll
    for (int i = 0; i < 16; i++) {
      unsigned ok = (unsigned)__shfl((int)kb, base + i, 64);
      int oid = __shfl(id, base + i, 64);
      rank += (ok > kb || (ok == kb && oid > id)) ? 1 : 0;
    }
    float wgt = (rank < 8) ? dotv : 0.0f;  // raw dot weight (vm[q] cancels)

    float ax = (pts[prow * 3 + 0] - vtx[q * 3 + 0]) * wgt;
    float ay = (pts[prow * 3 + 1] - vtx[q * 3 + 1]) * wgt;
    float az = (pts[prow * 3 + 2] - vtx[q * 3 + 2]) * wgt;
    float den = wgt;
#pragma unroll
    for (int m = 1; m <= 8; m <<= 1) {
      ax += __shfl_xor(ax, m, 64);
      ay += __shfl_xor(ay, m, 64);
      az += __shfl_xor(az, m, 64);
      den += __shfl_xor(den, m, 64);
    }
    if (c == 0) {
      float fx = ax / den, fy = ay / den, fz = az / den;
      flow_ws[q * 4 + 0] = fx;
      flow_ws[q * 4 + 1] = fy;
      flow_ws[q * 4 + 2] = fz;
      out[q * 4 + 0] = fx;
      out[q * 4 + 1] = fy;
      out[q * 4 + 2] = fz;
    }
  }

  // ---------------- phase B: KNN2 (keys = vf, visible only), 32 tiles ----
#pragma unroll
  for (int k = 0; k < 8; k++) { tvA[k] = 0u; tvB[k] = 0u; }
  {
    const float* mask = vm + batch * NVV;
    int bt0 = batch * 128 + ck * 64 + hf * 32;
    int tbase = ck * 64 + hf * 32;
    int tb16 = tbase * 16 + quad * 4;
    const float* mp0 = mask + tbase * 16 + quad * 4;
    short8 ah0, ah1, al0, al1, bh0, bh1, bl0, bl1;
    LOADK(ah0, ah1, al0, al1, vfh, vfl, bt0);
#pragma unroll 1
    for (int kt = 0; kt < 30; kt += 2) {
      LOADK(bh0, bh1, bl0, bl1, vfh, vfl, bt0 + kt + 1);
      COMP2(ah0, ah1, al0, al1, tb16 + kt * 16, mp0 + kt * 16);
      LOADK(ah0, ah1, al0, al1, vfh, vfl, bt0 + kt + 2);
      COMP2(bh0, bh1, bl0, bl1, tb16 + (kt + 1) * 16, mp0 + (kt + 1) * 16);
    }
    LOADK(bh0, bh1, bl0, bl1, vfh, vfl, bt0 + 31);
    COMP2(ah0, ah1, al0, al1, tb16 + 30 * 16, mp0 + 30 * 16);
    COMP2(bh0, bh1, bl0, bl1, tb16 + 31 * 16, mp0 + 31 * 16);
  }
#pragma unroll
  for (int k = 0; k < 8; k++) net8(tvA, tvB[k]);
#pragma unroll
  for (int m = 16; m <= 32; m <<= 1) {
    unsigned ov[8];
#pragma unroll
    for (int k = 0; k < 8; k++) ov[k] = (unsigned)__shfl_xor((int)tvA[k], m, 64);
#pragma unroll
    for (int k = 7; k >= 0; k--) net8(tvA, ov[k]);
  }
  if (hf == 1 && quad == 0) {
#pragma unroll
    for (int k = 0; k < 8; k++) mg[1][ck][col][k] = tvA[k];
  }
  __syncthreads();
  if (hf == 0 && quad == 0) {
#pragma unroll
    for (int k = 0; k < 8; k++) net8(tvA, mg[1][ck][col][k]);
    int q = qt_g * 16 + col;
#pragma unroll
    for (int k = 0; k < 8; k++)
      pc2[(size_t)(ck * 8 + k) * NQ + q] = tvA[k];
  }
}

// ===== kernel 3: exact re-rank of 16 KNN2 candidates + interpolate invisible =====
// R21 rank-selection version (XCD-pinned).
__global__ __launch_bounds__(256) void k_merge_final(const unsigned* __restrict__ pc,
                                                     const float* __restrict__ vf,
                                                     const float* __restrict__ vm,
                                                     const float* __restrict__ inv_vf_s,
                                                     const float* __restrict__ flow_ws,
                                                     float* __restrict__ out) {
  int p = blockIdx.x;
  int xcd = p & 7, jj = p >> 3;
  int lb = xcd * 128 + jj;            // batch == xcd
  int T = lb * 256 + (int)threadIdx.x;
  int q = T >> 4, c = T & 15, batch = q >> 11;
  if (vm[q] >= 0.5f) return;          // whole 16-group exits together
  int lane = (int)threadIdx.x & 63;
  int base = lane & 48;

  unsigned pk = pc[(size_t)c * NQ + q];
  bool valid = pk > 0xFFFu;           // 0 = masked sentinel
  int id = (int)(pk & 0xFFFu);
  int krow = batch * NVV + id;
  const float4* qp = (const float4*)(vf + (size_t)q * DD);
  float dotv = dot64(qp, (const float4*)(vf + (size_t)krow * DD));
  float s = dotv * inv_vf_s[krow];
  unsigned kb = valid ? fkey(s) : 0u;

  int rank = 0;
#pragma unroll
  for (int i = 0; i < 16; i++) {
    unsigned ok = (unsigned)__shfl((int)kb, base + i, 64);
    int oid = __shfl(id, base + i, 64);
    rank += (ok > kb || (ok == kb && oid > id)) ? 1 : 0;
  }
  float wgt = (valid && rank < 8) ? dotv : 0.0f;

  float ax = flow_ws[krow * 4 + 0] * wgt;
  float ay = flow_ws[krow * 4 + 1] * wgt;
  float az = flow_ws[krow * 4 + 2] * wgt;
  float den = wgt;
#pragma unroll
  for (int m = 1; m <= 8; m <<= 1) {
    ax += __shfl_xor(ax, m, 64);
    ay += __shfl_xor(ay, m, 64);
    az += __shfl_xor(az, m, 64);
    den += __shfl_xor(den, m, 64);
  }
  if (c == 0) {
    out[q * 4 + 0] = ax / den;
    out[q * 4 + 1] = ay / den;
    out[q * 4 + 2] = az / den;
  }
}

extern "C" void kernel_launch(void* const* d_in, const int* in_sizes, int n_in,
                              void* d_out, int out_size, void* d_ws, size_t ws_size,
                              hipStream_t stream) {
  const float* vtx = (const float*)d_in[0];
  const float* pts = (const float*)d_in[1];
  const float* vf = (const float*)d_in[2];
  const float* pf = (const float*)d_in[3];
  const float* lg = (const float*)d_in[4];
  float* out = (float*)d_out;
  float* ws = (float*)d_ws;

  float* vm = ws;
  float* inv_vf_s = ws + 16384;
  float* inv_pf_s = ws + 32768;
  float* flow = ws + 65536;
  unsigned* pc2 = (unsigned*)(ws + 393216);
  unsigned short* vfh = (unsigned short*)(ws + 655360);
  unsigned short* vfl = (unsigned short*)(ws + 1179648);   // +524288 floats
  unsigned short* pfh = (unsigned short*)(ws + 1703936);   // +524288
  unsigned short* pfl = (unsigned short*)(ws + 2752512);   // +1048576

  k_prep<<<BB + 768, 256, 0, stream>>>(lg, vf, pf, vm, inv_vf_s, inv_pf_s,
                                       vfh, vfl, pfh, pfl, out);
  k_knn<<<1024, 256, 0, stream>>>(vfh, vfl, pfh, pfl, vm, pc2,
                                  vf, pf, pts, vtx, inv_pf_s, flow, out);
  k_merge_final<<<NQ * 16 / 256, 256, 0, stream>>>(pc2, vf, vm, inv_vf_s,
                                                   flow, out);
}

// Round 11
// 162.713 us; speedup vs baseline: 1.1056x; 1.0072x over previous
//
#include <hip/hip_runtime.h>
#include <math.h>

#define BB 8
#define NVV 2048
#define NPP 4096
#define DD 64
#define NQ (BB * NVV)     // 16384 vertex rows
#define QT (NQ / 16)      // 1024 query tiles

typedef __attribute__((ext_vector_type(8))) short short8;
typedef __attribute__((ext_vector_type(8))) unsigned short ushort8;
typedef __attribute__((ext_vector_type(4))) float f32x4;

// ws layout (float offsets), audited line-by-line (R10 lesson):
// vm      @0        (16384)
// inv_vf_s@16384    (16384)   = 16384/norm
// inv_pf_s@32768    (32768)
// flow    @65536    (65536)
// pc1     @131072   (unused since R23 fold; layout kept)
// pc2     @393216   (16*16384 uints = 262144)
// vfh     @655360   (QT*1024 ushorts = 524288 floats)
// vfl     @1179648  (+524288)
// pfh     @1703936  (2048 tiles*1024 ushorts = 1048576 floats)
// pfl     @2752512  (+1048576)
// end     @3801088  floats = 14.5 MB

__device__ __forceinline__ unsigned short bf16rn(float x) {
  unsigned u = __float_as_uint(x);
  return (unsigned short)((u + 0x7FFFu + ((u >> 16) & 1u)) >> 16);
}
__device__ __forceinline__ float bf2f(unsigned short h) {
  return __uint_as_float(((unsigned)h) << 16);
}

// Branchless sorted-ascending top-8 insert: 7x v_med3_u32 + 1x max.
__device__ __forceinline__ void net8(unsigned* a, unsigned v) {
#pragma unroll
  for (int k = 0; k < 7; k++) {
    unsigned r;
    asm("v_med3_u32 %0, %1, %2, %3" : "=v"(r) : "v"(v), "v"(a[k]), "v"(a[k + 1]));
    a[k] = r;
  }
  a[7] = a[7] > v ? a[7] : v;
}

__device__ __forceinline__ float dot64(const float4* __restrict__ a,
                                       const float4* __restrict__ b) {
  float a0 = 0.f, a1 = 0.f, a2 = 0.f, a3 = 0.f;
#pragma unroll
  for (int c = 0; c < 16; c++) {
    float4 x = a[c], y = b[c];
    a0 = fmaf(x.x, y.x, a0);
    a1 = fmaf(x.y, y.y, a1);
    a2 = fmaf(x.z, y.z, a2);
    a3 = fmaf(x.w, y.w, a3);
  }
  return (a0 + a1) + (a2 + a3);
}

// sortable u32 from fp32: monotone bijection (total order preserved)
__device__ __forceinline__ unsigned fkey(float s) {
  unsigned u = __float_as_uint(s);
  return ((int)u < 0) ? ~u : (u | 0x80000000u);
}

// ===== kernel 1: staging (blocks 0..767, XCD-pinned) + vm (768..775) =====
// R24: XCD-pin k_prep with the SAME batch<->XCD map as k_knn. Staging
// block s: xcd=s&7, kk=s>>3 in [0,96); kk<32 -> the batch's 128 vf tiles,
// else its 256 pf tiles. vm block for batch b at bid=768+b ((768+b)&7==b).
// Effect: each XCD's L2 ends k_prep holding its batch's fp32 pf/vf AND
// staged bf16 -> k_knn (main loop + fused epilogue's fp32 dot64 rows)
// reads become L2 hits (R23's FETCH doubling = cold fp32 pf was the
// epilogue regression). Math bit-identical.
__global__ __launch_bounds__(256) void k_prep(const float* __restrict__ logits,
                                              const float* __restrict__ vf,
                                              const float* __restrict__ pf,
                                              float* __restrict__ vm,
                                              float* __restrict__ inv_vf_s,
                                              float* __restrict__ inv_pf_s,
                                              unsigned short* __restrict__ vfh,
                                              unsigned short* __restrict__ vfl,
                                              unsigned short* __restrict__ pfh,
                                              unsigned short* __restrict__ pfl,
                                              float* __restrict__ out) {
  int bid = blockIdx.x, t = threadIdx.x;
  if (bid >= 768) {
    int b = bid - 768;                 // batch b on XCD b
    __shared__ float smn[4], smx[4];
    float vals[8];
    float mn = 1e30f, mx = -1e30f;
#pragma unroll
    for (int i = 0; i < 8; i++) {
      float x = logits[b * NVV + t + i * 256];
      float s = 1.0f / (1.0f + expf(-x));
      vals[i] = s;
      mn = fminf(mn, s);
      mx = fmaxf(mx, s);
    }
    for (int o = 32; o; o >>= 1) {
      mn = fminf(mn, __shfl_xor(mn, o, 64));
      mx = fmaxf(mx, __shfl_xor(mx, o, 64));
    }
    int w = t >> 6;
    if ((t & 63) == 0) { smn[w] = mn; smx[w] = mx; }
    __syncthreads();
    mn = fminf(fminf(smn[0], smn[1]), fminf(smn[2], smn[3]));
    mx = fmaxf(fmaxf(smx[0], smx[1]), fmaxf(smx[2], smx[3]));
    float range = mx - mn;
#pragma unroll
    for (int i = 0; i < 8; i++) {
      float v = (vals[i] - mn) / range;
      int g = b * NVV + t + i * 256;
      vm[g] = v;
      out[g * 4 + 3] = v;
    }
  } else {
    // XCD-pinned staging: batch == bid&7
    int xcd = bid & 7, kk = bid >> 3;  // kk in [0,96)
    int wsel = t >> 6;
    int lane = t & 63, c = lane & 15, quad = (lane >> 4) & 3;
    const float* src;
    unsigned short *dh, *dl;
    float* ginv;
    int tile;
    if (kk < 32) {                     // 32 blocks x 4 waves = 128 vf tiles
      tile = xcd * 128 + kk * 4 + wsel;
      src = vf; dh = vfh; dl = vfl; ginv = inv_vf_s;
    } else {                           // 64 blocks x 4 waves = 256 pf tiles
      tile = xcd * 256 + (kk - 32) * 4 + wsel;
      src = pf; dh = pfh; dl = pfl; ginv = inv_pf_s;
    }
    int row = tile * 16 + c;
    const float* rp = src + (size_t)row * DD + quad * 8;
    float4 a0 = *(const float4*)(rp);
    float4 b0 = *(const float4*)(rp + 4);
    float4 a1 = *(const float4*)(rp + 32);
    float4 b1 = *(const float4*)(rp + 36);
    float xs[16] = {a0.x, a0.y, a0.z, a0.w, b0.x, b0.y, b0.z, b0.w,
                    a1.x, a1.y, a1.z, a1.w, b1.x, b1.y, b1.z, b1.w};
    float ss = 0.f;
#pragma unroll
    for (int j = 0; j < 16; j++) ss = fmaf(xs[j], xs[j], ss);
    ss += __shfl_xor(ss, 16, 64);
    ss += __shfl_xor(ss, 32, 64);   // all quads now hold the row total
    float inv = 1.0f / fmaxf(sqrtf(ss), 1e-12f);
    if (quad == 0) ginv[row] = 16384.0f * inv;  // pow2 scale: exact ratio later
    ushort8 h, l;
    size_t s0 = (size_t)tile * 128 + lane;      // kk=0 slot
#pragma unroll
    for (int j = 0; j < 8; j++) {
      float xn = xs[j] * inv;
      unsigned short hj = bf16rn(xn);
      h[j] = hj;
      l[j] = bf16rn(xn - bf2f(hj));
    }
    *(ushort8*)(dh + s0 * 8) = h;
    *(ushort8*)(dl + s0 * 8) = l;
#pragma unroll
    for (int j = 0; j < 8; j++) {
      float xn = xs[8 + j] * inv;
      unsigned short hj = bf16rn(xn);
      h[j] = hj;
      l[j] = bf16rn(xn - bf2f(hj));
    }
    *(ushort8*)(dh + (s0 + 64) * 8) = h;      // kk=1 slot
    *(ushort8*)(dl + (s0 + 64) * 8) = l;
  }
}

// R20 k_knn inner-loop machinery (kept verbatim)
#define LOADK(d0, d1, d2, d3, KH, KL, tile) do {            \
    size_t bo_ = (size_t)(tile) * 1024 + lane * 8;          \
    d0 = *(const short8*)((KH) + bo_);                      \
    d1 = *(const short8*)((KH) + bo_ + 512);                \
    d2 = *(const short8*)((KL) + bo_);                      \
    d3 = *(const short8*)((KL) + bo_ + 512);                \
  } while (0)

#define MFMA6(c_, h0_, h1_, l0_, l1_) do {                                  \
    c_ = __builtin_amdgcn_mfma_f32_16x16x32_bf16(h0_, qh0, c_, 0, 0, 0);    \
    c_ = __builtin_amdgcn_mfma_f32_16x16x32_bf16(h1_, qh1, c_, 0, 0, 0);    \
    c_ = __builtin_amdgcn_mfma_f32_16x16x32_bf16(h0_, ql0, c_, 0, 0, 0);    \
    c_ = __builtin_amdgcn_mfma_f32_16x16x32_bf16(h1_, ql1, c_, 0, 0, 0);    \
    c_ = __builtin_amdgcn_mfma_f32_16x16x32_bf16(l0_, qh0, c_, 0, 0, 0);    \
    c_ = __builtin_amdgcn_mfma_f32_16x16x32_bf16(l1_, qh1, c_, 0, 0, 0);    \
  } while (0)

#define COMP1(h0_, h1_, l0_, l1_, b16_) do {                                \
    f32x4 c_ = {0.f, 0.f, 0.f, 0.f};                                        \
    MFMA6(c_, h0_, h1_, l0_, l1_);                                          \
    unsigned u0_ = (unsigned)fmaxf(fmaf(c_[0], 520000.0f, 520000.0f), 0.0f);\
    net8(tvA, (u0_ << 12) | (unsigned)((b16_) + 0));                        \
    unsigned u1_ = (unsigned)fmaxf(fmaf(c_[1], 520000.0f, 520000.0f), 0.0f);\
    net8(tvA, (u1_ << 12) | (unsigned)((b16_) + 1));                        \
    unsigned u2_ = (unsigned)fmaxf(fmaf(c_[2], 520000.0f, 520000.0f), 0.0f);\
    net8(tvB, (u2_ << 12) | (unsigned)((b16_) + 2));                        \
    unsigned u3_ = (unsigned)fmaxf(fmaf(c_[3], 520000.0f, 520000.0f), 0.0f);\
    net8(tvB, (u3_ << 12) | (unsigned)((b16_) + 3));                        \
  } while (0)

#define COMP2(h0_, h1_, l0_, l1_, b16_, mp_) do {                           \
    float4 mv_ = *(const float4*)(mp_);                                     \
    f32x4 c_ = {0.f, 0.f, 0.f, 0.f};                                        \
    MFMA6(c_, h0_, h1_, l0_, l1_);                                          \
    unsigned u0_ = (unsigned)fmaxf(fmaf(c_[0], 520000.0f, 520000.0f), 0.0f);\
    unsigned p0_ = (u0_ << 12) | (unsigned)((b16_) + 0);                    \
    net8(tvA, (mv_.x >= 0.5f) ? p0_ : 0u);                                  \
    unsigned u1_ = (unsigned)fmaxf(fmaf(c_[1], 520000.0f, 520000.0f), 0.0f);\
    unsigned p1_ = (u1_ << 12) | (unsigned)((b16_) + 1);                    \
    net8(tvA, (mv_.y >= 0.5f) ? p1_ : 0u);                                  \
    unsigned u2_ = (unsigned)fmaxf(fmaf(c_[2], 520000.0f, 520000.0f), 0.0f);\
    unsigned p2_ = (u2_ << 12) | (unsigned)((b16_) + 2);                    \
    net8(tvB, (mv_.z >= 0.5f) ? p2_ : 0u);                                  \
    unsigned u3_ = (unsigned)fmaxf(fmaf(c_[3], 520000.0f, 520000.0f), 0.0f);\
    unsigned p3_ = (u3_ << 12) | (unsigned)((b16_) + 3);                    \
    net8(tvB, (mv_.w >= 0.5f) ? p3_ : 0u);                                  \
  } while (0)

// ===== kernel 2: MFMA KNN + fused exact KNN1 re-rank & flow =====
// R24: epilogue moved AFTER phase B (R23 had it mid-kernel: phase A ->
// cold-fp32 scattered epilogue -> phase B created a convoy; back-to-back
// A/B restores the R20 77us main-loop structure, and the epilogue's
// latency tail lands at kernel end where block drain overlaps it).
// cand[] LDS survives phase B (disjoint from mg); phase-B barriers
// provide the ordering. Math bit-identical to R23.
__global__ __launch_bounds__(256)
void k_knn(const unsigned short* __restrict__ vfh, const unsigned short* __restrict__ vfl,
           const unsigned short* __restrict__ pfh, const unsigned short* __restrict__ pfl,
           const float* __restrict__ vm, unsigned* __restrict__ pc2,
           const float* __restrict__ vf, const float* __restrict__ pf,
           const float* __restrict__ pts, const float* __restrict__ vtx,
           const float* __restrict__ inv_pf_s,
           float* __restrict__ flow_ws, float* __restrict__ out) {
  __shared__ unsigned mg[2][2][16][8];   // [section][ck][col][k]
  __shared__ unsigned cand[16][16];      // [q-in-tile][candidate]

  int p = blockIdx.x;                 // 0..1023
  int xcd = p & 7, j = p >> 3;        // batch pin: batch == xcd
  int qt_g = xcd * 128 + j;           // this block's query tile
  int batch = xcd;
  int w = (int)threadIdx.x >> 6;      // wave 0..3
  int ck = w >> 1, hf = w & 1;        // chunk, half within chunk
  int lane = threadIdx.x & 63, col = lane & 15, quad = lane >> 4;

  // query frags once per wave (serve both phases)
  size_t ab = (size_t)qt_g * 1024 + lane * 8;
  short8 qh0 = *(const short8*)(vfh + ab);
  short8 qh1 = *(const short8*)(vfh + ab + 512);
  short8 ql0 = *(const short8*)(vfl + ab);
  short8 ql1 = *(const short8*)(vfl + ab + 512);
  // Pin loop-invariant query frags in AGPRs: MFMA reads AGPR A/B natively.
  asm volatile("" : "+a"(qh0), "+a"(qh1), "+a"(ql0), "+a"(ql1));

  unsigned tvA[8], tvB[8];

  // ---------------- phase A: KNN1 (keys = pf), 64 tiles ----------------
#pragma unroll
  for (int k = 0; k < 8; k++) { tvA[k] = 0u; tvB[k] = 0u; }
  {
    int bt0 = batch * 256 + ck * 128 + hf * 64;
    int tb16 = (ck * 128 + hf * 64) * 16 + quad * 4;
    short8 ah0, ah1, al0, al1, bh0, bh1, bl0, bl1;
    LOADK(ah0, ah1, al0, al1, pfh, pfl, bt0);
#pragma unroll 1
    for (int kt = 0; kt < 62; kt += 2) {
      LOADK(bh0, bh1, bl0, bl1, pfh, pfl, bt0 + kt + 1);
      COMP1(ah0, ah1, al0, al1, tb16 + kt * 16);
      LOADK(ah0, ah1, al0, al1, pfh, pfl, bt0 + kt + 2);
      COMP1(bh0, bh1, bl0, bl1, tb16 + (kt + 1) * 16);
    }
    LOADK(bh0, bh1, bl0, bl1, pfh, pfl, bt0 + 63);
    COMP1(ah0, ah1, al0, al1, tb16 + 62 * 16);
    COMP1(bh0, bh1, bl0, bl1, tb16 + 63 * 16);
  }
  // exact union of the two chains
#pragma unroll
  for (int k = 0; k < 8; k++) net8(tvA, tvB[k]);
  // butterfly across quads (lane bits 4,5) -- all quads end identical
#pragma unroll
  for (int m = 16; m <= 32; m <<= 1) {
    unsigned ov[8];
#pragma unroll
    for (int k = 0; k < 8; k++) ov[k] = (unsigned)__shfl_xor((int)tvA[k], m, 64);
#pragma unroll
    for (int k = 7; k >= 0; k--) net8(tvA, ov[k]);
  }
  if (hf == 1 && quad == 0) {
#pragma unroll
    for (int k = 0; k < 8; k++) mg[0][ck][col][k] = tvA[k];
  }
  __syncthreads();
  if (hf == 0 && quad == 0) {
#pragma unroll
    for (int k = 0; k < 8; k++) net8(tvA, mg[0][ck][col][k]);
#pragma unroll
    for (int k = 0; k < 8; k++)
      cand[col][ck * 8 + k] = tvA[k];
  }

  // ---------------- phase B: KNN2 (keys = vf, visible only), 32 tiles ----
#pragma unroll
  for (int k = 0; k < 8; k++) { tvA[k] = 0u; tvB[k] = 0u; }
  {
    const float* mask = vm + batch * NVV;
    int bt0 = batch * 128 + ck * 64 + hf * 32;
    int tbase = ck * 64 + hf * 32;
    int tb16 = tbase * 16 + quad * 4;
    const float* mp0 = mask + tbase * 16 + quad * 4;
    short8 ah0, ah1, al0, al1, bh0, bh1, bl0, bl1;
    LOADK(ah0, ah1, al0, al1, vfh, vfl, bt0);
#pragma unroll 1
    for (int kt = 0; kt < 30; kt += 2) {
      LOADK(bh0, bh1, bl0, bl1, vfh, vfl, bt0 + kt + 1);
      COMP2(ah0, ah1, al0, al1, tb16 + kt * 16, mp0 + kt * 16);
      LOADK(ah0, ah1, al0, al1, vfh, vfl, bt0 + kt + 2);
      COMP2(bh0, bh1, bl0, bl1, tb16 + (kt + 1) * 16, mp0 + (kt + 1) * 16);
    }
    LOADK(bh0, bh1, bl0, bl1, vfh, vfl, bt0 + 31);
    COMP2(ah0, ah1, al0, al1, tb16 + 30 * 16, mp0 + 30 * 16);
    COMP2(bh0, bh1, bl0, bl1, tb16 + 31 * 16, mp0 + 31 * 16);
  }
#pragma unroll
  for (int k = 0; k < 8; k++) net8(tvA, tvB[k]);
#pragma unroll
  for (int m = 16; m <= 32; m <<= 1) {
    unsigned ov[8];
#pragma unroll
    for (int k = 0; k < 8; k++) ov[k] = (unsigned)__shfl_xor((int)tvA[k], m, 64);
#pragma unroll
    for (int k = 7; k >= 0; k--) net8(tvA, ov[k]);
  }
  if (hf == 1 && quad == 0) {
#pragma unroll
    for (int k = 0; k < 8; k++) mg[1][ck][col][k] = tvA[k];
  }
  __syncthreads();
  if (hf == 0 && quad == 0) {
#pragma unroll
    for (int k = 0; k < 8; k++) net8(tvA, mg[1][ck][col][k]);
    int q = qt_g * 16 + col;
#pragma unroll
    for (int k = 0; k < 8; k++)
      pc2[(size_t)(ck * 8 + k) * NQ + q] = tvA[k];
  }
  __syncthreads();   // cand[] writes (phase A) ordered before epilogue reads

  // ------- fused exact re-rank of 16 KNN1 candidates + flow (R21 body) -------
  {
    int t = (int)threadIdx.x;
    int qloc = t >> 4, c = t & 15;
    int q = qt_g * 16 + qloc;
    int base = lane & 48;               // 16-lane group start (same as R21)

    unsigned pk = cand[qloc][c];
    int id = (int)(pk & 0xFFFu);
    int prow = batch * NPP + id;
    const float4* qp = (const float4*)(vf + (size_t)q * DD);
    float dotv = dot64(qp, (const float4*)(pf + (size_t)prow * DD));
    float s = dotv * inv_pf_s[prow];    // exact cosine * 2^14 (uniform pow2 scale)
    unsigned kb = fkey(s);

    int rank = 0;
#pragma unroll
    for (int i = 0; i < 16; i++) {
      unsigned ok = (unsigned)__shfl((int)kb, base + i, 64);
      int oid = __shfl(id, base + i, 64);
      rank += (ok > kb || (ok == kb && oid > id)) ? 1 : 0;
    }
    float wgt = (rank < 8) ? dotv : 0.0f;  // raw dot weight (vm[q] cancels)

    float ax = (pts[prow * 3 + 0] - vtx[q * 3 + 0]) * wgt;
    float ay = (pts[prow * 3 + 1] - vtx[q * 3 + 1]) * wgt;
    float az = (pts[prow * 3 + 2] - vtx[q * 3 + 2]) * wgt;
    float den = wgt;
#pragma unroll
    for (int m = 1; m <= 8; m <<= 1) {
      ax += __shfl_xor(ax, m, 64);
      ay += __shfl_xor(ay, m, 64);
      az += __shfl_xor(az, m, 64);
      den += __shfl_xor(den, m, 64);
    }
    if (c == 0) {
      float fx = ax / den, fy = ay / den, fz = az / den;
      flow_ws[q * 4 + 0] = fx;
      flow_ws[q * 4 + 1] = fy;
      flow_ws[q * 4 + 2] = fz;
      out[q * 4 + 0] = fx;
      out[q * 4 + 1] = fy;
      out[q * 4 + 2] = fz;
    }
  }
}

// ===== kernel 3: exact re-rank of 16 KNN2 candidates + interpolate invisible =====
// R21 rank-selection version (XCD-pinned).
__global__ __launch_bounds__(256) void k_merge_final(const unsigned* __restrict__ pc,
                                                     const float* __restrict__ vf,
                                                     const float* __restrict__ vm,
                                                     const float* __restrict__ inv_vf_s,
                                                     const float* __restrict__ flow_ws,
                                                     float* __restrict__ out) {
  int p = blockIdx.x;
  int xcd = p & 7, jj = p >> 3;
  int lb = xcd * 128 + jj;            // batch == xcd
  int T = lb * 256 + (int)threadIdx.x;
  int q = T >> 4, c = T & 15, batch = q >> 11;
  if (vm[q] >= 0.5f) return;          // whole 16-group exits together
  int lane = (int)threadIdx.x & 63;
  int base = lane & 48;

  unsigned pk = pc[(size_t)c * NQ + q];
  bool valid = pk > 0xFFFu;           // 0 = masked sentinel
  int id = (int)(pk & 0xFFFu);
  int krow = batch * NVV + id;
  const float4* qp = (const float4*)(vf + (size_t)q * DD);
  float dotv = dot64(qp, (const float4*)(vf + (size_t)krow * DD));
  float s = dotv * inv_vf_s[krow];
  unsigned kb = valid ? fkey(s) : 0u;

  int rank = 0;
#pragma unroll
  for (int i = 0; i < 16; i++) {
    unsigned ok = (unsigned)__shfl((int)kb, base + i, 64);
    int oid = __shfl(id, base + i, 64);
    rank += (ok > kb || (ok == kb && oid > id)) ? 1 : 0;
  }
  float wgt = (valid && rank < 8) ? dotv : 0.0f;

  float ax = flow_ws[krow * 4 + 0] * wgt;
  float ay = flow_ws[krow * 4 + 1] * wgt;
  float az = flow_ws[krow * 4 + 2] * wgt;
  float den = wgt;
#pragma unroll
  for (int m = 1; m <= 8; m <<= 1) {
    ax += __shfl_xor(ax, m, 64);
    ay += __shfl_xor(ay, m, 64);
    az += __shfl_xor(az, m, 64);
    den += __shfl_xor(den, m, 64);
  }
  if (c == 0) {
    out[q * 4 + 0] = ax / den;
    out[q * 4 + 1] = ay / den;
    out[q * 4 + 2] = az / den;
  }
}

extern "C" void kernel_launch(void* const* d_in, const int* in_sizes, int n_in,
                              void* d_out, int out_size, void* d_ws, size_t ws_size,
                              hipStream_t stream) {
  const float* vtx = (const float*)d_in[0];
  const float* pts = (const float*)d_in[1];
  const float* vf = (const float*)d_in[2];
  const float* pf = (const float*)d_in[3];
  const float* lg = (const float*)d_in[4];
  float* out = (float*)d_out;
  float* ws = (float*)d_ws;

  float* vm = ws;
  float* inv_vf_s = ws + 16384;
  float* inv_pf_s = ws + 32768;
  float* flow = ws + 65536;
  unsigned* pc2 = (unsigned*)(ws + 393216);
  unsigned short* vfh = (unsigned short*)(ws + 655360);
  unsigned short* vfl = (unsigned short*)(ws + 1179648);   // +524288 floats
  unsigned short* pfh = (unsigned short*)(ws + 1703936);   // +524288
  unsigned short* pfl = (unsigned short*)(ws + 2752512);   // +1048576

  k_prep<<<768 + BB, 256, 0, stream>>>(lg, vf, pf, vm, inv_vf_s, inv_pf_s,
                                       vfh, vfl, pfh, pfl, out);
  k_knn<<<1024, 256, 0, stream>>>(vfh, vfl, pfh, pfl, vm, pc2,
                                  vf, pf, pts, vtx, inv_pf_s, flow, out);
  k_merge_final<<<NQ * 16 / 256, 256, 0, stream>>>(pc2, vf, vm, inv_vf_s,
                                                   flow, out);
}